// Round 2
// baseline (474.571 us; speedup 1.0000x reference)
//
#include <hip/hip_runtime.h>

typedef short short8 __attribute__((ext_vector_type(8)));
typedef short short4_t __attribute__((ext_vector_type(4)));
typedef float floatx4 __attribute__((ext_vector_type(4)));
typedef unsigned short ushort_t;

#define B_ 16
#define S_ 128
#define T_ 64
#define H_ 128
#define FF_ 256
#define SCALEQK 0.25f

// bf16 transposed-weight pool offsets (ushort units)
#define OFFP 0
#define OFFQ(l) (16384 + (l) * 65536)
#define OFFK(l) (OFFQ(l) + 16384)
#define OFFV(l) (OFFQ(l) + 32768)
#define OFFO(l) (OFFQ(l) + 49152)
#define OFFW1(l) (278528 + (l) * 65536)
#define OFFW2(l) (OFFW1(l) + 32768)

__device__ __forceinline__ float b2f(ushort_t u) {
    union { unsigned int i; float f; } x; x.i = ((unsigned int)u) << 16; return x.f;
}
__device__ __forceinline__ ushort_t f2b(float f) {
    union { float f; unsigned int i; } x; x.f = f;
    unsigned int r = x.i + 0x7fffu + ((x.i >> 16) & 1u);
    return (ushort_t)(r >> 16);
}
__device__ __forceinline__ int pack2b(float a, float b) {
    return (int)f2b(a) | ((int)f2b(b) << 16);
}

// ---------------------------------------------------------------------------
// Weight preconvert: fp32 W[K][N] -> bf16 wT[N][K] (round-2 proven).
// ---------------------------------------------------------------------------
struct WtEnt { const float* src; int N; int K; int nclog2; int dstoff; };
struct WtArgs { WtEnt e[25]; };

__global__ __launch_bounds__(256) void wt_kernel(WtArgs a, ushort_t* __restrict__ dst) {
    WtEnt ent = a.e[blockIdx.x];
    const int tiles_c = ent.N >> 5;
    const int nt = (ent.K >> 5) * tiles_c;
    const int t = blockIdx.y;
    if (t >= nt) return;
    const int tc = t & (tiles_c - 1);
    const int tr = t >> ent.nclog2;
    __shared__ float ld[32 * 33];
    const int tid = threadIdx.x;
#pragma unroll
    for (int i = 0; i < 4; ++i) {
        int e = tid + i * 256;
        int rr = e >> 5, cc = e & 31;
        ld[rr * 33 + cc] = ent.src[(tr * 32 + rr) * ent.N + tc * 32 + cc];
    }
    __syncthreads();
    ushort_t* d = dst + ent.dstoff;
#pragma unroll
    for (int i = 0; i < 4; ++i) {
        int e = tid + i * 256;
        int rr = e >> 5, cc = e & 31;
        d[(tc * 32 + rr) * ent.K + tr * 32 + cc] = f2b(ld[cc * 33 + rr]);
    }
}

// ---------------------------------------------------------------------------
// Round-5 proven helpers (verbatim, templates generic in RT/CT/JT).
// ---------------------------------------------------------------------------
template<int RT, int CT, int KK>
__device__ __forceinline__ void mm_g(const ushort_t* aL, int sa,
                                     const ushort_t* __restrict__ wT,
                                     int colbase, int lane, floatx4 (&acc)[RT][CT]) {
    const int l15 = lane & 15, lq8 = (lane >> 4) * 8;
#pragma unroll
    for (int r = 0; r < RT; ++r)
#pragma unroll
        for (int c = 0; c < CT; ++c) acc[r][c] = (floatx4){0.f, 0.f, 0.f, 0.f};
#pragma unroll
    for (int k0 = 0; k0 < KK; k0 += 32) {
        short8 b[CT];
#pragma unroll
        for (int c = 0; c < CT; ++c)
            b[c] = *(const short8*)&wT[(colbase + c * 16 + l15) * KK + k0 + lq8];
#pragma unroll
        for (int r = 0; r < RT; ++r) {
            short8 a = *(const short8*)&aL[(r * 16 + l15) * sa + k0 + lq8];
#pragma unroll
            for (int c = 0; c < CT; ++c)
                acc[r][c] = __builtin_amdgcn_mfma_f32_16x16x32_bf16(a, b[c], acc[r][c], 0, 0, 0);
        }
    }
}

template<int RT, int CT>
__device__ __forceinline__ void add_bias(floatx4 (&acc)[RT][CT], const float* b,
                                         int colbase, int l15) {
#pragma unroll
    for (int c = 0; c < CT; ++c) {
        float bc = b[colbase + c * 16 + l15];
#pragma unroll
        for (int r = 0; r < RT; ++r)
#pragma unroll
            for (int g = 0; g < 4; ++g) acc[r][c][g] += bc;
    }
}

template<int RT, int CT>
__device__ __forceinline__ void add_resid_reg(floatx4 (&acc)[RT][CT],
                                              const float (&res)[RT][CT][4]) {
#pragma unroll
    for (int r = 0; r < RT; ++r)
#pragma unroll
        for (int c = 0; c < CT; ++c)
#pragma unroll
            for (int g = 0; g < 4; ++g) acc[r][c][g] += res[r][c][g];
}
template<int RT, int CT>
__device__ __forceinline__ void save_resid(float (&res)[RT][CT][4],
                                           const floatx4 (&acc)[RT][CT]) {
#pragma unroll
    for (int r = 0; r < RT; ++r)
#pragma unroll
        for (int c = 0; c < CT; ++c)
#pragma unroll
            for (int g = 0; g < 4; ++g) res[r][c][g] = acc[r][c][g];
}

template<int RT, int CT>
__device__ __forceinline__ void st_n(const floatx4 (&acc)[RT][CT], ushort_t* dst, int stride,
                                     int colbase, int l15, int lq) {
#pragma unroll
    for (int r = 0; r < RT; ++r)
#pragma unroll
        for (int g = 0; g < 4; ++g) {
            int row = r * 16 + lq * 4 + g;
#pragma unroll
            for (int c = 0; c < CT; ++c)
                dst[row * stride + colbase + c * 16 + l15] = f2b(acc[r][c][g]);
        }
}

template<int RT, int CT>
__device__ __forceinline__ void st_t(const floatx4 (&acc)[RT][CT], ushort_t* dst, int stride,
                                     int colbase, int l15, int lq) {
#pragma unroll
    for (int r = 0; r < RT; ++r)
#pragma unroll
        for (int c = 0; c < CT; ++c) {
            int d = colbase + c * 16 + l15;
            short4_t p;
#pragma unroll
            for (int g = 0; g < 4; ++g) p[g] = (short)f2b(acc[r][c][g]);
            *(short4_t*)&dst[d * stride + r * 16 + lq * 4] = p;
        }
}

template<int RT, int CT>
__device__ __forceinline__ void ln_norm(floatx4 (&acc)[RT][CT], float* redL,
                                        const float* lns, const float* lnb,
                                        int colbase, int l15, int lq, int wv) {
#pragma unroll
    for (int r = 0; r < RT; ++r)
#pragma unroll
        for (int g = 0; g < 4; ++g) {
            float s = 0.f, q = 0.f;
#pragma unroll
            for (int c = 0; c < CT; ++c) { float v = acc[r][c][g]; s += v; q += v * v; }
            s += __shfl_xor(s, 1); s += __shfl_xor(s, 2); s += __shfl_xor(s, 4); s += __shfl_xor(s, 8);
            q += __shfl_xor(q, 1); q += __shfl_xor(q, 2); q += __shfl_xor(q, 4); q += __shfl_xor(q, 8);
            if (l15 == 0) {
                int row = r * 16 + lq * 4 + g;
                redL[row * 8 + wv] = s;
                redL[row * 8 + 4 + wv] = q;
            }
        }
    __syncthreads();
#pragma unroll
    for (int r = 0; r < RT; ++r)
#pragma unroll
        for (int g = 0; g < 4; ++g) {
            int row = r * 16 + lq * 4 + g;
            float4 S = *(float4*)&redL[row * 8];
            float4 Q = *(float4*)&redL[row * 8 + 4];
            float mean = (S.x + S.y + S.z + S.w) * (1.f / 128.f);
            float var = (Q.x + Q.y + Q.z + Q.w) * (1.f / 128.f) - mean * mean;
            float rstd = rsqrtf(var + 1e-5f);
#pragma unroll
            for (int c = 0; c < CT; ++c) {
                int col = colbase + c * 16 + l15;
                acc[r][c][g] = (acc[r][c][g] - mean) * rstd * lns[col] + lnb[col];
            }
        }
}

template<int JT>
__device__ __forceinline__ void softmax_pack(floatx4 (&st)[JT], bool iv, unsigned jm,
                                             int (&px)[JT][2]) {
    float ev[JT][4];
    float mx = -3.0e38f;
#pragma unroll
    for (int jt = 0; jt < JT; ++jt)
#pragma unroll
        for (int g = 0; g < 4; ++g) {
            bool ok = iv && ((jm >> (jt * 4 + g)) & 1u);
            float s = ok ? st[jt][g] * SCALEQK : -1e9f;
            ev[jt][g] = s; mx = fmaxf(mx, s);
        }
    mx = fmaxf(mx, __shfl_xor(mx, 16)); mx = fmaxf(mx, __shfl_xor(mx, 32));
    float sum = 0.f;
#pragma unroll
    for (int jt = 0; jt < JT; ++jt)
#pragma unroll
        for (int g = 0; g < 4; ++g) { float e = __expf(ev[jt][g] - mx); ev[jt][g] = e; sum += e; }
    sum += __shfl_xor(sum, 16); sum += __shfl_xor(sum, 32);
    float inv = 1.f / sum;
#pragma unroll
    for (int jt = 0; jt < JT; ++jt) {
        px[jt][0] = pack2b(ev[jt][0] * inv, ev[jt][1] * inv);
        px[jt][1] = pack2b(ev[jt][2] * inv, ev[jt][3] * inv);
    }
}

__device__ __forceinline__ short8 pfrag(const int (*px)[2], int jc, int lq, int l15) {
    const int jA = (lq & 1) * 32 + l15;
    int a0 = __shfl(px[jc * 2][0], jA);
    int a1 = __shfl(px[jc * 2][1], jA);
    int a2 = __shfl(px[jc * 2][0], jA + 16);
    int a3 = __shfl(px[jc * 2][1], jA + 16);
    int b0 = __shfl(px[jc * 2 + 1][0], jA);
    int b1 = __shfl(px[jc * 2 + 1][1], jA);
    int b2 = __shfl(px[jc * 2 + 1][0], jA + 16);
    int b3 = __shfl(px[jc * 2 + 1][1], jA + 16);
    const bool t = (lq >> 1) != 0;
    union { int4 i; short8 s; } u;
    u.i = make_int4(t ? b0 : a0, t ? b1 : a1, t ? b2 : a2, t ? b3 : a3);
    return u.s;
}
__device__ __forceinline__ short8 vfrag(const ushort_t* vT, int stride, int row, int off) {
    int2 a = *(const int2*)&vT[row * stride + off];
    int2 b = *(const int2*)&vT[row * stride + off + 4];
    union { int4 i; short8 s; } u;
    u.i = make_int4(a.x, a.y, b.x, b.y);
    return u.s;
}

// ---------------------------------------------------------------------------
// K1 (round-5 proven, verbatim): per group gid (64 rows): input proj -> L0
// full -> L1 (kv + q@t0 + attn). Writes o1[gid][128] bf16 + xr0f[gid][128]
// fp32. 2048 blocks x 256 thr.
// ---------------------------------------------------------------------------
__global__ __launch_bounds__(256, 2) void k1_mega(
    const float* __restrict__ poly, const int* __restrict__ lens,
    const ushort_t* __restrict__ wt,
    const float* __restrict__ projb, const float* __restrict__ pls,
    const float* __restrict__ plb, const float* __restrict__ pos,
    const float* __restrict__ bq0, const float* __restrict__ bk0,
    const float* __restrict__ bv0, const float* __restrict__ bo0,
    const float* __restrict__ l1s0, const float* __restrict__ l1b0,
    const float* __restrict__ b10, const float* __restrict__ b20,
    const float* __restrict__ l2s0, const float* __restrict__ l2b0,
    const float* __restrict__ bq1, const float* __restrict__ bk1,
    const float* __restrict__ bv1,
    ushort_t* __restrict__ o1, float* __restrict__ xr0f)
{
    __shared__ ushort_t pool[34816];
    __shared__ float redL[512];
    __shared__ float psL[8 * 68];
    __shared__ float q1L[128];
    ushort_t* xL = pool;            // [64][136]
    ushort_t* qL = pool + 8704;     // [64][136]  (o written in-place per head)
    ushort_t* kL = pool + 17408;    // [64][136]
    ushort_t* vT = pool + 26112;    // [128][68]  v transposed
    ushort_t* hL = pool + 17408;    // [64][272]  FFN hidden, overlays kL+vT

    const int tid = threadIdx.x, lane = tid & 63, wv = tid >> 6;
    const int l15 = lane & 15, lq = lane >> 4;
    const int gid = blockIdx.x;
    const int len = lens[gid];

    // ---- stage poly -> xL (bf16, -1 pad) ----
    {
        const float* pg = poly + (size_t)gid * 8192;
#pragma unroll
        for (int it = 0; it < 8; ++it) {
            int e4 = (tid + it * 256) * 4;
            int row = e4 >> 7, col = e4 & 127;
            float4 f = *(const float4*)(pg + e4);
            if (row >= len) { f.x = -1.f; f.y = -1.f; f.z = -1.f; f.w = -1.f; }
            short4_t u;
            u[0] = (short)f2b(f.x); u[1] = (short)f2b(f.y);
            u[2] = (short)f2b(f.z); u[3] = (short)f2b(f.w);
            *(short4_t*)&xL[row * 136 + col] = u;
        }
    }
    __syncthreads();

    floatx4 a2[4][2];
    float xre[4][2][4];             // fp32 residual stream (this thread's slice)

    // ---- P1: input proj + LN + relu + pos -> xre, xL ----
    mm_g<4, 2, 128>(xL, 136, wt + OFFP, wv * 32, lane, a2);
    add_bias<4, 2>(a2, projb, wv * 32, l15);
    ln_norm<4, 2>(a2, redL, pls, plb, wv * 32, l15, lq, wv);
    __syncthreads();               // done reading xL (staged poly) before overwrite
#pragma unroll
    for (int r = 0; r < 4; ++r)
#pragma unroll
        for (int gg = 0; gg < 4; ++gg) {
            int row = r * 16 + lq * 4 + gg;
#pragma unroll
            for (int c = 0; c < 2; ++c) {
                int col = wv * 32 + c * 16 + l15;
                float v = fmaxf(a2[r][c][gg], 0.f) + pos[row * 128 + col];
                xre[r][c][gg] = v;
                xL[row * 136 + col] = f2b(v);
            }
        }
    __syncthreads();

    // ---- P2: L0 QKV ----
    mm_g<4, 2, 128>(xL, 136, wt + OFFQ(0), wv * 32, lane, a2);
    add_bias<4, 2>(a2, bq0, wv * 32, l15);
    st_n<4, 2>(a2, qL, 136, wv * 32, l15, lq);
    mm_g<4, 2, 128>(xL, 136, wt + OFFK(0), wv * 32, lane, a2);
    add_bias<4, 2>(a2, bk0, wv * 32, l15);
    st_n<4, 2>(a2, kL, 136, wv * 32, l15, lq);
    mm_g<4, 2, 128>(xL, 136, wt + OFFV(0), wv * 32, lane, a2);
    add_bias<4, 2>(a2, bv0, wv * 32, l15);
    st_t<4, 2>(a2, vT, 68, wv * 32, l15, lq);
    __syncthreads();

    // ---- P3: L0 attention (MFMA S^T, reg softmax, shuffle-PV) ----
    {
        const int iRow = wv * 16 + l15;
        const bool iv = iRow < len;
        unsigned jm = 0;
#pragma unroll
        for (int jt = 0; jt < 4; ++jt)
#pragma unroll
            for (int gg = 0; gg < 4; ++gg)
                if (jt * 16 + lq * 4 + gg < len) jm |= (1u << (jt * 4 + gg));
        for (int h = 0; h < 8; ++h) {
            const int hc = h * 16;
            short8 z8 = {0, 0, 0, 0, 0, 0, 0, 0};
            short8 bqf = z8;
            if (lq < 2) bqf = *(const short8*)&qL[iRow * 136 + hc + lq * 8];
            floatx4 st[4];
#pragma unroll
            for (int jt = 0; jt < 4; ++jt) {
                short8 ak = z8;
                if (lq < 2) ak = *(const short8*)&kL[(jt * 16 + l15) * 136 + hc + lq * 8];
                floatx4 zz = {0.f, 0.f, 0.f, 0.f};
                st[jt] = __builtin_amdgcn_mfma_f32_16x16x32_bf16(ak, bqf, zz, 0, 0, 0);
            }
            int px[4][2];
            softmax_pack<4>(st, iv, jm, px);
            floatx4 ao = {0.f, 0.f, 0.f, 0.f};
#pragma unroll
            for (int jc = 0; jc < 2; ++jc) {
                short8 av = vfrag(vT, 68, hc + l15, jc * 32 + lq * 8);
                short8 bp = pfrag(px, jc, lq, l15);
                ao = __builtin_amdgcn_mfma_f32_16x16x32_bf16(av, bp, ao, 0, 0, 0);
            }
            short4_t w;
#pragma unroll
            for (int gg = 0; gg < 4; ++gg) w[gg] = (short)f2b(ao[gg]);
            *(short4_t*)&qL[iRow * 136 + hc + lq * 4] = w;
        }
    }
    __syncthreads();

    // ---- P4: O-proj + resid + LN -> xre, xL ----
    mm_g<4, 2, 128>(qL, 136, wt + OFFO(0), wv * 32, lane, a2);
    add_bias<4, 2>(a2, bo0, wv * 32, l15);
    add_resid_reg<4, 2>(a2, xre);
    ln_norm<4, 2>(a2, redL, l1s0, l1b0, wv * 32, l15, lq, wv);
    save_resid<4, 2>(xre, a2);
    st_n<4, 2>(a2, xL, 136, wv * 32, l15, lq);
    __syncthreads();

    // ---- P5: FFN W1 + relu -> hL ----
    {
        floatx4 a4[4][4];
        mm_g<4, 4, 128>(xL, 136, wt + OFFW1(0), wv * 64, lane, a4);
        add_bias<4, 4>(a4, b10, wv * 64, l15);
#pragma unroll
        for (int r = 0; r < 4; ++r)
#pragma unroll
            for (int c = 0; c < 4; ++c)
#pragma unroll
                for (int gg = 0; gg < 4; ++gg) a4[r][c][gg] = fmaxf(a4[r][c][gg], 0.f);
        st_n<4, 4>(a4, hL, 272, wv * 64, l15, lq);
    }
    __syncthreads();

    // ---- P6: FFN W2 + resid + LN -> xre, xL; row0 -> xr0f (fp32) ----
    mm_g<4, 2, 256>(hL, 272, wt + OFFW2(0), wv * 32, lane, a2);
    add_bias<4, 2>(a2, b20, wv * 32, l15);
    add_resid_reg<4, 2>(a2, xre);
    ln_norm<4, 2>(a2, redL, l2s0, l2b0, wv * 32, l15, lq, wv);
    save_resid<4, 2>(xre, a2);
    st_n<4, 2>(a2, xL, 136, wv * 32, l15, lq);
    if (lq == 0) {
#pragma unroll
        for (int c = 0; c < 2; ++c)
            xr0f[(size_t)gid * 128 + wv * 32 + c * 16 + l15] = a2[0][c][0];   // row 0
    }
    __syncthreads();

    // ---- P7: L1 K,V (full) + q at t=0 ----
    mm_g<4, 2, 128>(xL, 136, wt + OFFK(1), wv * 32, lane, a2);
    add_bias<4, 2>(a2, bk1, wv * 32, l15);
    st_n<4, 2>(a2, kL, 136, wv * 32, l15, lq);
    mm_g<4, 2, 128>(xL, 136, wt + OFFV(1), wv * 32, lane, a2);
    add_bias<4, 2>(a2, bv1, wv * 32, l15);
    st_t<4, 2>(a2, vT, 68, wv * 32, l15, lq);
    if (tid < 128) {
        int d = tid;
        float a = bq1[d];
        const ushort_t* wq = wt + OFFQ(1) + d * 128;
#pragma unroll 4
        for (int j0 = 0; j0 < 128; j0 += 8) {
            short8 w8 = *(const short8*)&wq[j0];
            short8 x8 = *(const short8*)&xL[j0];
#pragma unroll
            for (int q = 0; q < 8; ++q)
                a = fmaf(b2f((ushort_t)x8[q]), b2f((ushort_t)w8[q]), a);
        }
        q1L[d] = a;
    }
    __syncthreads();

    // ---- P8: L1 single-query attention -> o1 ----
    {
        int h = tid >> 5, jj = tid & 31;
        int hc = h * 16;
        float s[2];
#pragma unroll
        for (int half = 0; half < 2; ++half) {
            int j = jj + half * 32;
            float a = 0.f;
            short8 k0v = *(const short8*)&kL[j * 136 + hc];
            short8 k1v = *(const short8*)&kL[j * 136 + hc + 8];
#pragma unroll
            for (int q = 0; q < 8; ++q) {
                a = fmaf(q1L[hc + q], b2f((ushort_t)k0v[q]), a);
                a = fmaf(q1L[hc + 8 + q], b2f((ushort_t)k1v[q]), a);
            }
            s[half] = (j < len) ? a * SCALEQK : -1e9f;
        }
        float mx = fmaxf(s[0], s[1]);
#pragma unroll
        for (int d = 1; d < 32; d <<= 1) mx = fmaxf(mx, __shfl_xor(mx, d));
        float e0 = __expf(s[0] - mx), e1 = __expf(s[1] - mx);
        float sum = e0 + e1;
#pragma unroll
        for (int d = 1; d < 32; d <<= 1) sum += __shfl_xor(sum, d);
        float inv = 1.f / sum;
        psL[h * 68 + jj] = e0 * inv;
        psL[h * 68 + jj + 32] = e1 * inv;
    }
    __syncthreads();
    if (tid < 128) {
        int h = tid >> 4, d = tid & 15, hc = h * 16;
        float a = 0.f;
#pragma unroll 4
        for (int j0 = 0; j0 < 64; j0 += 4) {
            float4 p4 = *(const float4*)&psL[h * 68 + j0];
            short4_t v4 = *(const short4_t*)&vT[(hc + d) * 68 + j0];
            a += p4.x * b2f((ushort_t)v4[0]) + p4.y * b2f((ushort_t)v4[1])
               + p4.z * b2f((ushort_t)v4[2]) + p4.w * b2f((ushort_t)v4[3]);
        }
        o1[(size_t)gid * 128 + hc + d] = f2b(a);
    }
}

// ---------------------------------------------------------------------------
// K2: fused tail. One block per spatial group b (t'=0): 128 rows x 128.
// Does: L1 O-proj+LN + FFN, then L2 and L3 full spatial blocks, final store.
// 16 blocks x 256 thr, everything resident in LDS. Replaces 13 launches.
// ---------------------------------------------------------------------------
__global__ __launch_bounds__(256, 1) void k2_mega(
    const ushort_t* __restrict__ o1, const float* __restrict__ xr0f,
    const int* __restrict__ lens, const ushort_t* __restrict__ wt,
    const float* __restrict__ bq, const float* __restrict__ bk,
    const float* __restrict__ bv, const float* __restrict__ bo,
    const float* __restrict__ l1s, const float* __restrict__ l1b,
    const float* __restrict__ b1, const float* __restrict__ b2,
    const float* __restrict__ l2s, const float* __restrict__ l2b,
    float* __restrict__ outp)
{
    __shared__ ushort_t pool[69632];    // 139264 B
    __shared__ float redL[1024];
    __shared__ int vldL[128];
    ushort_t* xL = pool;                // [128][136]
    ushort_t* qL = pool + 17408;        // [128][136] (attn o written in place)
    ushort_t* kL = pool + 34816;        // [128][136]
    ushort_t* vT = pool + 52224;        // [128][136] v transposed (d-major)
    ushort_t* hL = pool + 34816;        // [128][272] FFN hidden, overlays kL+vT

    const int tid = threadIdx.x, lane = tid & 63, wv = tid >> 6;
    const int l15 = lane & 15, lq = lane >> 4;
    const int b = blockIdx.x;
    const size_t rowg = (size_t)b * 128;

    // ---- stage o1 -> xL (bf16 copy) + validity ----
#pragma unroll
    for (int it = 0; it < 8; ++it) {
        int e8 = tid + it * 256;
        int row = e8 >> 4, kg = e8 & 15;
        *(short8*)&xL[row * 136 + kg * 8] = *(const short8*)&o1[(rowg + row) * 128 + kg * 8];
    }
    if (tid < 128) vldL[tid] = (lens[b * 128 + tid] > 0) ? 1 : 0;
    __syncthreads();

    // per-lane j-validity mask (same for both spatial layers): bit jt*4+g <-> j=jt*16+lq*4+g
    unsigned jm = 0;
#pragma unroll
    for (int jt = 0; jt < 8; ++jt)
#pragma unroll
        for (int g = 0; g < 4; ++g)
            if (vldL[jt * 16 + lq * 4 + g]) jm |= (1u << (jt * 4 + g));

    // residual stream (fp32, this thread's slice) seeded from xr0f
    float xre[8][2][4];
#pragma unroll
    for (int r = 0; r < 8; ++r)
#pragma unroll
        for (int c = 0; c < 2; ++c)
#pragma unroll
            for (int g = 0; g < 4; ++g)
                xre[r][c][g] = xr0f[(rowg + r * 16 + lq * 4 + g) * 128 + wv * 32 + c * 16 + l15];

    floatx4 a2[8][2];

    for (int l = 1; l < 4; ++l) {
        if (l >= 2) {
            // ---- QKV ----
            mm_g<8, 2, 128>(xL, 136, wt + OFFQ(l), wv * 32, lane, a2);
            add_bias<8, 2>(a2, bq + l * H_, wv * 32, l15);
            st_n<8, 2>(a2, qL, 136, wv * 32, l15, lq);
            mm_g<8, 2, 128>(xL, 136, wt + OFFK(l), wv * 32, lane, a2);
            add_bias<8, 2>(a2, bk + l * H_, wv * 32, l15);
            st_n<8, 2>(a2, kL, 136, wv * 32, l15, lq);
            mm_g<8, 2, 128>(xL, 136, wt + OFFV(l), wv * 32, lane, a2);
            add_bias<8, 2>(a2, bv + l * H_, wv * 32, l15);
            st_t<8, 2>(a2, vT, 136, wv * 32, l15, lq);
            __syncthreads();
            // ---- spatial attention (P3 pattern, 2 i-blocks of 64 rows) ----
            for (int h = 0; h < 8; ++h) {
                const int hc = h * 16;
#pragma unroll
                for (int iblk = 0; iblk < 2; ++iblk) {
                    const int iRow = iblk * 64 + wv * 16 + l15;
                    const bool iv = vldL[iRow] != 0;
                    short8 z8 = {0, 0, 0, 0, 0, 0, 0, 0};
                    short8 bqf = z8;
                    if (lq < 2) bqf = *(const short8*)&qL[iRow * 136 + hc + lq * 8];
                    floatx4 st[8];
#pragma unroll
                    for (int jt = 0; jt < 8; ++jt) {
                        short8 ak = z8;
                        if (lq < 2) ak = *(const short8*)&kL[(jt * 16 + l15) * 136 + hc + lq * 8];
                        floatx4 zz = {0.f, 0.f, 0.f, 0.f};
                        st[jt] = __builtin_amdgcn_mfma_f32_16x16x32_bf16(ak, bqf, zz, 0, 0, 0);
                    }
                    int px[8][2];
                    softmax_pack<8>(st, iv, jm, px);
                    floatx4 ao = {0.f, 0.f, 0.f, 0.f};
#pragma unroll
                    for (int jc = 0; jc < 4; ++jc) {
                        short8 av = vfrag(vT, 136, hc + l15, jc * 32 + lq * 8);
                        short8 bp = pfrag(px, jc, lq, l15);
                        ao = __builtin_amdgcn_mfma_f32_16x16x32_bf16(av, bp, ao, 0, 0, 0);
                    }
                    short4_t w;
#pragma unroll
                    for (int g = 0; g < 4; ++g) w[g] = (short)f2b(ao[g]);
                    *(short4_t*)&qL[iRow * 136 + hc + lq * 4] = w;
                }
            }
            __syncthreads();
        }

        // ---- O-proj + resid + LN -> xre, xL ----
        const ushort_t* aIn = (l == 1) ? xL : qL;
        mm_g<8, 2, 128>(aIn, 136, wt + OFFO(l), wv * 32, lane, a2);
        add_bias<8, 2>(a2, bo + l * H_, wv * 32, l15);
        add_resid_reg<8, 2>(a2, xre);
        ln_norm<8, 2>(a2, redL, l1s + l * H_, l1b + l * H_, wv * 32, l15, lq, wv);
        save_resid<8, 2>(xre, a2);
        st_n<8, 2>(a2, xL, 136, wv * 32, l15, lq);
        __syncthreads();

        // ---- FFN W1 + relu -> hL ----
        {
            floatx4 a4[8][4];
            mm_g<8, 4, 128>(xL, 136, wt + OFFW1(l), wv * 64, lane, a4);
            add_bias<8, 4>(a4, b1 + l * FF_, wv * 64, l15);
#pragma unroll
            for (int r = 0; r < 8; ++r)
#pragma unroll
                for (int c = 0; c < 4; ++c)
#pragma unroll
                    for (int g = 0; g < 4; ++g) a4[r][c][g] = fmaxf(a4[r][c][g], 0.f);
            st_n<8, 4>(a4, hL, 272, wv * 64, l15, lq);
        }
        __syncthreads();

        // ---- FFN W2 + resid + LN ----
        mm_g<8, 2, 256>(hL, 272, wt + OFFW2(l), wv * 32, lane, a2);
        add_bias<8, 2>(a2, b2 + l * H_, wv * 32, l15);
        add_resid_reg<8, 2>(a2, xre);
        ln_norm<8, 2>(a2, redL, l2s + l * H_, l2b + l * H_, wv * 32, l15, lq, wv);
        if (l == 3) {
            // final: rows s<64 -> out[b][s][col] fp32
#pragma unroll
            for (int r = 0; r < 4; ++r)
#pragma unroll
                for (int c = 0; c < 2; ++c)
#pragma unroll
                    for (int g = 0; g < 4; ++g) {
                        int row = r * 16 + lq * 4 + g;
                        outp[((size_t)(b * 64 + row)) * 128 + wv * 32 + c * 16 + l15] = a2[r][c][g];
                    }
        } else {
            save_resid<8, 2>(xre, a2);
            st_n<8, 2>(a2, xL, 136, wv * 32, l15, lq);
            __syncthreads();
        }
    }
}

// ---------------------------------------------------------------------------
extern "C" void kernel_launch(void* const* d_in, const int* in_sizes, int n_in,
                              void* d_out, int out_size, void* d_ws, size_t ws_size,
                              hipStream_t stream)
{
    const float* poly   = (const float*)d_in[0];
    const int*   lens   = (const int*)d_in[1];
    const float* proj_w = (const float*)d_in[2];
    const float* proj_b = (const float*)d_in[3];
    const float* pls    = (const float*)d_in[4];
    const float* plb    = (const float*)d_in[5];
    const float* pos    = (const float*)d_in[6];
    const float* Wq = (const float*)d_in[7];
    const float* bq = (const float*)d_in[8];
    const float* Wk = (const float*)d_in[9];
    const float* bk = (const float*)d_in[10];
    const float* Wv = (const float*)d_in[11];
    const float* bv = (const float*)d_in[12];
    const float* Wo = (const float*)d_in[13];
    const float* bo = (const float*)d_in[14];
    const float* l1s = (const float*)d_in[15];
    const float* l1b = (const float*)d_in[16];
    const float* W1 = (const float*)d_in[17];
    const float* b1 = (const float*)d_in[18];
    const float* W2 = (const float*)d_in[19];
    const float* b2 = (const float*)d_in[20];
    const float* l2s = (const float*)d_in[21];
    const float* l2b = (const float*)d_in[22];
    float* outp = (float*)d_out;

    char* base = (char*)d_ws;
    ushort_t* wt    = (ushort_t*)base;                 // 540672 bf16 = 1,081,344 B
    ushort_t* o1buf = (ushort_t*)(base + 1081344);     // [2048][128] bf16
    float* xr0f     = (float*)(base + 1605632);        // [2048][128] fp32

    const int HH = H_ * H_, HF = H_ * FF_;
    WtArgs wa;
    wa.e[0] = {proj_w, 128, 128, 2, OFFP};
    for (int l = 0; l < 4; ++l) {
        wa.e[1 + l * 4 + 0] = {Wq + l * HH, 128, 128, 2, OFFQ(l)};
        wa.e[1 + l * 4 + 1] = {Wk + l * HH, 128, 128, 2, OFFK(l)};
        wa.e[1 + l * 4 + 2] = {Wv + l * HH, 128, 128, 2, OFFV(l)};
        wa.e[1 + l * 4 + 3] = {Wo + l * HH, 128, 128, 2, OFFO(l)};
    }
    for (int l = 0; l < 4; ++l) {
        wa.e[17 + l * 2 + 0] = {W1 + l * HF, 256, 128, 3, OFFW1(l)};
        wa.e[17 + l * 2 + 1] = {W2 + l * HF, 128, 256, 2, OFFW2(l)};
    }
    wt_kernel<<<dim3(25, 32), 256, 0, stream>>>(wa, wt);

    // ---- fused input-proj + L0 + L1(kv,q,attn) ----
    k1_mega<<<dim3(2048), 256, 0, stream>>>(
        poly, lens, wt,
        proj_b, pls, plb, pos,
        bq, bk, bv, bo, l1s, l1b, b1, b2, l2s, l2b,
        bq + H_, bk + H_, bv + H_,
        o1buf, xr0f);

    // ---- fused tail: L1 O-proj/FFN + spatial layers 2,3 + final store ----
    k2_mega<<<dim3(16), 256, 0, stream>>>(
        o1buf, xr0f, lens, wt,
        bq, bk, bv, bo, l1s, l1b, b1, b2, l2s, l2b,
        outp);
}

// Round 3
// 468.946 us; speedup vs baseline: 1.0120x; 1.0120x over previous
//
#include <hip/hip_runtime.h>

typedef short short8 __attribute__((ext_vector_type(8)));
typedef short short4_t __attribute__((ext_vector_type(4)));
typedef float floatx4 __attribute__((ext_vector_type(4)));
typedef unsigned short ushort_t;

#define B_ 16
#define S_ 128
#define T_ 64
#define H_ 128
#define FF_ 256
#define SCALEQK 0.25f

// bf16 transposed-weight pool offsets (ushort units)
#define OFFP 0
#define OFFQ(l) (16384 + (l) * 65536)
#define OFFK(l) (OFFQ(l) + 16384)
#define OFFV(l) (OFFQ(l) + 32768)
#define OFFO(l) (OFFQ(l) + 49152)
#define OFFW1(l) (278528 + (l) * 65536)
#define OFFW2(l) (OFFW1(l) + 32768)

__device__ __forceinline__ float b2f(ushort_t u) {
    union { unsigned int i; float f; } x; x.i = ((unsigned int)u) << 16; return x.f;
}
__device__ __forceinline__ ushort_t f2b(float f) {
    union { float f; unsigned int i; } x; x.f = f;
    unsigned int r = x.i + 0x7fffu + ((x.i >> 16) & 1u);
    return (ushort_t)(r >> 16);
}
__device__ __forceinline__ int pack2b(float a, float b) {
    return (int)f2b(a) | ((int)f2b(b) << 16);
}

// ---------------------------------------------------------------------------
// Weight preconvert: fp32 W[K][N] -> bf16 wT[N][K] (round-2 proven).
// ---------------------------------------------------------------------------
struct WtEnt { const float* src; int N; int K; int nclog2; int dstoff; };
struct WtArgs { WtEnt e[25]; };

__global__ __launch_bounds__(256) void wt_kernel(WtArgs a, ushort_t* __restrict__ dst) {
    WtEnt ent = a.e[blockIdx.x];
    const int tiles_c = ent.N >> 5;
    const int nt = (ent.K >> 5) * tiles_c;
    const int t = blockIdx.y;
    if (t >= nt) return;
    const int tc = t & (tiles_c - 1);
    const int tr = t >> ent.nclog2;
    __shared__ float ld[32 * 33];
    const int tid = threadIdx.x;
#pragma unroll
    for (int i = 0; i < 4; ++i) {
        int e = tid + i * 256;
        int rr = e >> 5, cc = e & 31;
        ld[rr * 33 + cc] = ent.src[(tr * 32 + rr) * ent.N + tc * 32 + cc];
    }
    __syncthreads();
    ushort_t* d = dst + ent.dstoff;
#pragma unroll
    for (int i = 0; i < 4; ++i) {
        int e = tid + i * 256;
        int rr = e >> 5, cc = e & 31;
        d[(tc * 32 + rr) * ent.K + tr * 32 + cc] = f2b(ld[cc * 33 + rr]);
    }
}

// ---------------------------------------------------------------------------
// Proven helpers (templates generic in RT/CT/JT).
// ---------------------------------------------------------------------------
template<int RT, int CT, int KK>
__device__ __forceinline__ void mm_g(const ushort_t* aL, int sa,
                                     const ushort_t* __restrict__ wT,
                                     int colbase, int lane, floatx4 (&acc)[RT][CT]) {
    const int l15 = lane & 15, lq8 = (lane >> 4) * 8;
#pragma unroll
    for (int r = 0; r < RT; ++r)
#pragma unroll
        for (int c = 0; c < CT; ++c) acc[r][c] = (floatx4){0.f, 0.f, 0.f, 0.f};
#pragma unroll
    for (int k0 = 0; k0 < KK; k0 += 32) {
        short8 b[CT];
#pragma unroll
        for (int c = 0; c < CT; ++c)
            b[c] = *(const short8*)&wT[(colbase + c * 16 + l15) * KK + k0 + lq8];
#pragma unroll
        for (int r = 0; r < RT; ++r) {
            short8 a = *(const short8*)&aL[(r * 16 + l15) * sa + k0 + lq8];
#pragma unroll
            for (int c = 0; c < CT; ++c)
                acc[r][c] = __builtin_amdgcn_mfma_f32_16x16x32_bf16(a, b[c], acc[r][c], 0, 0, 0);
        }
    }
}

template<int RT, int CT>
__device__ __forceinline__ void add_bias(floatx4 (&acc)[RT][CT], const float* b,
                                         int colbase, int l15) {
#pragma unroll
    for (int c = 0; c < CT; ++c) {
        float bc = b[colbase + c * 16 + l15];
#pragma unroll
        for (int r = 0; r < RT; ++r)
#pragma unroll
            for (int g = 0; g < 4; ++g) acc[r][c][g] += bc;
    }
}

template<int RT, int CT>
__device__ __forceinline__ void add_resid_reg(floatx4 (&acc)[RT][CT],
                                              const float (&res)[RT][CT][4]) {
#pragma unroll
    for (int r = 0; r < RT; ++r)
#pragma unroll
        for (int c = 0; c < CT; ++c)
#pragma unroll
            for (int g = 0; g < 4; ++g) acc[r][c][g] += res[r][c][g];
}
template<int RT, int CT>
__device__ __forceinline__ void save_resid(float (&res)[RT][CT][4],
                                           const floatx4 (&acc)[RT][CT]) {
#pragma unroll
    for (int r = 0; r < RT; ++r)
#pragma unroll
        for (int c = 0; c < CT; ++c)
#pragma unroll
            for (int g = 0; g < 4; ++g) res[r][c][g] = acc[r][c][g];
}

template<int RT, int CT>
__device__ __forceinline__ void st_n(const floatx4 (&acc)[RT][CT], ushort_t* dst, int stride,
                                     int colbase, int l15, int lq) {
#pragma unroll
    for (int r = 0; r < RT; ++r)
#pragma unroll
        for (int g = 0; g < 4; ++g) {
            int row = r * 16 + lq * 4 + g;
#pragma unroll
            for (int c = 0; c < CT; ++c)
                dst[row * stride + colbase + c * 16 + l15] = f2b(acc[r][c][g]);
        }
}

template<int RT, int CT>
__device__ __forceinline__ void st_t(const floatx4 (&acc)[RT][CT], ushort_t* dst, int stride,
                                     int colbase, int l15, int lq) {
#pragma unroll
    for (int r = 0; r < RT; ++r)
#pragma unroll
        for (int c = 0; c < CT; ++c) {
            int d = colbase + c * 16 + l15;
            short4_t p;
#pragma unroll
            for (int g = 0; g < 4; ++g) p[g] = (short)f2b(acc[r][c][g]);
            *(short4_t*)&dst[d * stride + r * 16 + lq * 4] = p;
        }
}

// k1 version: 4 col-waves, rows 0..63 (wv = col-wave index)
template<int RT, int CT>
__device__ __forceinline__ void ln_norm(floatx4 (&acc)[RT][CT], float* redL,
                                        const float* lns, const float* lnb,
                                        int colbase, int l15, int lq, int wv) {
#pragma unroll
    for (int r = 0; r < RT; ++r)
#pragma unroll
        for (int g = 0; g < 4; ++g) {
            float s = 0.f, q = 0.f;
#pragma unroll
            for (int c = 0; c < CT; ++c) { float v = acc[r][c][g]; s += v; q += v * v; }
            s += __shfl_xor(s, 1); s += __shfl_xor(s, 2); s += __shfl_xor(s, 4); s += __shfl_xor(s, 8);
            q += __shfl_xor(q, 1); q += __shfl_xor(q, 2); q += __shfl_xor(q, 4); q += __shfl_xor(q, 8);
            if (l15 == 0) {
                int row = r * 16 + lq * 4 + g;
                redL[row * 8 + wv] = s;
                redL[row * 8 + 4 + wv] = q;
            }
        }
    __syncthreads();
#pragma unroll
    for (int r = 0; r < RT; ++r)
#pragma unroll
        for (int g = 0; g < 4; ++g) {
            int row = r * 16 + lq * 4 + g;
            float4 S = *(float4*)&redL[row * 8];
            float4 Q = *(float4*)&redL[row * 8 + 4];
            float mean = (S.x + S.y + S.z + S.w) * (1.f / 128.f);
            float var = (Q.x + Q.y + Q.z + Q.w) * (1.f / 128.f) - mean * mean;
            float rstd = rsqrtf(var + 1e-5f);
#pragma unroll
            for (int c = 0; c < CT; ++c) {
                int col = colbase + c * 16 + l15;
                acc[r][c][g] = (acc[r][c][g] - mean) * rstd * lns[col] + lnb[col];
            }
        }
}

// k2 version: 2-D wave grid — wc = col-wave (0..3), rowbase = row-wave * 32.
template<int RT, int CT>
__device__ __forceinline__ void ln_normW(floatx4 (&acc)[RT][CT], float* redL,
                                         const float* lns, const float* lnb,
                                         int colbase, int rowbase, int l15, int lq, int wc) {
#pragma unroll
    for (int r = 0; r < RT; ++r)
#pragma unroll
        for (int g = 0; g < 4; ++g) {
            float s = 0.f, q = 0.f;
#pragma unroll
            for (int c = 0; c < CT; ++c) { float v = acc[r][c][g]; s += v; q += v * v; }
            s += __shfl_xor(s, 1); s += __shfl_xor(s, 2); s += __shfl_xor(s, 4); s += __shfl_xor(s, 8);
            q += __shfl_xor(q, 1); q += __shfl_xor(q, 2); q += __shfl_xor(q, 4); q += __shfl_xor(q, 8);
            if (l15 == 0) {
                int row = rowbase + r * 16 + lq * 4 + g;
                redL[row * 8 + wc] = s;
                redL[row * 8 + 4 + wc] = q;
            }
        }
    __syncthreads();
#pragma unroll
    for (int r = 0; r < RT; ++r)
#pragma unroll
        for (int g = 0; g < 4; ++g) {
            int row = rowbase + r * 16 + lq * 4 + g;
            float4 S = *(float4*)&redL[row * 8];
            float4 Q = *(float4*)&redL[row * 8 + 4];
            float mean = (S.x + S.y + S.z + S.w) * (1.f / 128.f);
            float var = (Q.x + Q.y + Q.z + Q.w) * (1.f / 128.f) - mean * mean;
            float rstd = rsqrtf(var + 1e-5f);
#pragma unroll
            for (int c = 0; c < CT; ++c) {
                int col = colbase + c * 16 + l15;
                acc[r][c][g] = (acc[r][c][g] - mean) * rstd * lns[col] + lnb[col];
            }
        }
}

template<int JT>
__device__ __forceinline__ void softmax_pack(floatx4 (&st)[JT], bool iv, unsigned jm,
                                             int (&px)[JT][2]) {
    float ev[JT][4];
    float mx = -3.0e38f;
#pragma unroll
    for (int jt = 0; jt < JT; ++jt)
#pragma unroll
        for (int g = 0; g < 4; ++g) {
            bool ok = iv && ((jm >> (jt * 4 + g)) & 1u);
            float s = ok ? st[jt][g] * SCALEQK : -1e9f;
            ev[jt][g] = s; mx = fmaxf(mx, s);
        }
    mx = fmaxf(mx, __shfl_xor(mx, 16)); mx = fmaxf(mx, __shfl_xor(mx, 32));
    float sum = 0.f;
#pragma unroll
    for (int jt = 0; jt < JT; ++jt)
#pragma unroll
        for (int g = 0; g < 4; ++g) { float e = __expf(ev[jt][g] - mx); ev[jt][g] = e; sum += e; }
    sum += __shfl_xor(sum, 16); sum += __shfl_xor(sum, 32);
    float inv = 1.f / sum;
#pragma unroll
    for (int jt = 0; jt < JT; ++jt) {
        px[jt][0] = pack2b(ev[jt][0] * inv, ev[jt][1] * inv);
        px[jt][1] = pack2b(ev[jt][2] * inv, ev[jt][3] * inv);
    }
}

__device__ __forceinline__ short8 pfrag(const int (*px)[2], int jc, int lq, int l15) {
    const int jA = (lq & 1) * 32 + l15;
    int a0 = __shfl(px[jc * 2][0], jA);
    int a1 = __shfl(px[jc * 2][1], jA);
    int a2 = __shfl(px[jc * 2][0], jA + 16);
    int a3 = __shfl(px[jc * 2][1], jA + 16);
    int b0 = __shfl(px[jc * 2 + 1][0], jA);
    int b1 = __shfl(px[jc * 2 + 1][1], jA);
    int b2 = __shfl(px[jc * 2 + 1][0], jA + 16);
    int b3 = __shfl(px[jc * 2 + 1][1], jA + 16);
    const bool t = (lq >> 1) != 0;
    union { int4 i; short8 s; } u;
    u.i = make_int4(t ? b0 : a0, t ? b1 : a1, t ? b2 : a2, t ? b3 : a3);
    return u.s;
}
__device__ __forceinline__ short8 vfrag(const ushort_t* vT, int stride, int row, int off) {
    int2 a = *(const int2*)&vT[row * stride + off];
    int2 b = *(const int2*)&vT[row * stride + off + 4];
    union { int4 i; short8 s; } u;
    u.i = make_int4(a.x, a.y, b.x, b.y);
    return u.s;
}

// ---------------------------------------------------------------------------
// K1 (round-5 proven, verbatim): per group gid (64 rows): input proj -> L0
// full -> L1 (kv + q@t0 + attn). Writes o1[gid][128] bf16 + xr0f[gid][128]
// fp32. 2048 blocks x 256 thr.
// ---------------------------------------------------------------------------
__global__ __launch_bounds__(256, 2) void k1_mega(
    const float* __restrict__ poly, const int* __restrict__ lens,
    const ushort_t* __restrict__ wt,
    const float* __restrict__ projb, const float* __restrict__ pls,
    const float* __restrict__ plb, const float* __restrict__ pos,
    const float* __restrict__ bq0, const float* __restrict__ bk0,
    const float* __restrict__ bv0, const float* __restrict__ bo0,
    const float* __restrict__ l1s0, const float* __restrict__ l1b0,
    const float* __restrict__ b10, const float* __restrict__ b20,
    const float* __restrict__ l2s0, const float* __restrict__ l2b0,
    const float* __restrict__ bq1, const float* __restrict__ bk1,
    const float* __restrict__ bv1,
    ushort_t* __restrict__ o1, float* __restrict__ xr0f)
{
    __shared__ ushort_t pool[34816];
    __shared__ float redL[512];
    __shared__ float psL[8 * 68];
    __shared__ float q1L[128];
    ushort_t* xL = pool;            // [64][136]
    ushort_t* qL = pool + 8704;     // [64][136]  (o written in-place per head)
    ushort_t* kL = pool + 17408;    // [64][136]
    ushort_t* vT = pool + 26112;    // [128][68]  v transposed
    ushort_t* hL = pool + 17408;    // [64][272]  FFN hidden, overlays kL+vT

    const int tid = threadIdx.x, lane = tid & 63, wv = tid >> 6;
    const int l15 = lane & 15, lq = lane >> 4;
    const int gid = blockIdx.x;
    const int len = lens[gid];

    // ---- stage poly -> xL (bf16, -1 pad) ----
    {
        const float* pg = poly + (size_t)gid * 8192;
#pragma unroll
        for (int it = 0; it < 8; ++it) {
            int e4 = (tid + it * 256) * 4;
            int row = e4 >> 7, col = e4 & 127;
            float4 f = *(const float4*)(pg + e4);
            if (row >= len) { f.x = -1.f; f.y = -1.f; f.z = -1.f; f.w = -1.f; }
            short4_t u;
            u[0] = (short)f2b(f.x); u[1] = (short)f2b(f.y);
            u[2] = (short)f2b(f.z); u[3] = (short)f2b(f.w);
            *(short4_t*)&xL[row * 136 + col] = u;
        }
    }
    __syncthreads();

    floatx4 a2[4][2];
    float xre[4][2][4];             // fp32 residual stream (this thread's slice)

    // ---- P1: input proj + LN + relu + pos -> xre, xL ----
    mm_g<4, 2, 128>(xL, 136, wt + OFFP, wv * 32, lane, a2);
    add_bias<4, 2>(a2, projb, wv * 32, l15);
    ln_norm<4, 2>(a2, redL, pls, plb, wv * 32, l15, lq, wv);
    __syncthreads();               // done reading xL (staged poly) before overwrite
#pragma unroll
    for (int r = 0; r < 4; ++r)
#pragma unroll
        for (int gg = 0; gg < 4; ++gg) {
            int row = r * 16 + lq * 4 + gg;
#pragma unroll
            for (int c = 0; c < 2; ++c) {
                int col = wv * 32 + c * 16 + l15;
                float v = fmaxf(a2[r][c][gg], 0.f) + pos[row * 128 + col];
                xre[r][c][gg] = v;
                xL[row * 136 + col] = f2b(v);
            }
        }
    __syncthreads();

    // ---- P2: L0 QKV ----
    mm_g<4, 2, 128>(xL, 136, wt + OFFQ(0), wv * 32, lane, a2);
    add_bias<4, 2>(a2, bq0, wv * 32, l15);
    st_n<4, 2>(a2, qL, 136, wv * 32, l15, lq);
    mm_g<4, 2, 128>(xL, 136, wt + OFFK(0), wv * 32, lane, a2);
    add_bias<4, 2>(a2, bk0, wv * 32, l15);
    st_n<4, 2>(a2, kL, 136, wv * 32, l15, lq);
    mm_g<4, 2, 128>(xL, 136, wt + OFFV(0), wv * 32, lane, a2);
    add_bias<4, 2>(a2, bv0, wv * 32, l15);
    st_t<4, 2>(a2, vT, 68, wv * 32, l15, lq);
    __syncthreads();

    // ---- P3: L0 attention (MFMA S^T, reg softmax, shuffle-PV) ----
    {
        const int iRow = wv * 16 + l15;
        const bool iv = iRow < len;
        unsigned jm = 0;
#pragma unroll
        for (int jt = 0; jt < 4; ++jt)
#pragma unroll
            for (int gg = 0; gg < 4; ++gg)
                if (jt * 16 + lq * 4 + gg < len) jm |= (1u << (jt * 4 + gg));
        for (int h = 0; h < 8; ++h) {
            const int hc = h * 16;
            short8 z8 = {0, 0, 0, 0, 0, 0, 0, 0};
            short8 bqf = z8;
            if (lq < 2) bqf = *(const short8*)&qL[iRow * 136 + hc + lq * 8];
            floatx4 st[4];
#pragma unroll
            for (int jt = 0; jt < 4; ++jt) {
                short8 ak = z8;
                if (lq < 2) ak = *(const short8*)&kL[(jt * 16 + l15) * 136 + hc + lq * 8];
                floatx4 zz = {0.f, 0.f, 0.f, 0.f};
                st[jt] = __builtin_amdgcn_mfma_f32_16x16x32_bf16(ak, bqf, zz, 0, 0, 0);
            }
            int px[4][2];
            softmax_pack<4>(st, iv, jm, px);
            floatx4 ao = {0.f, 0.f, 0.f, 0.f};
#pragma unroll
            for (int jc = 0; jc < 2; ++jc) {
                short8 av = vfrag(vT, 68, hc + l15, jc * 32 + lq * 8);
                short8 bp = pfrag(px, jc, lq, l15);
                ao = __builtin_amdgcn_mfma_f32_16x16x32_bf16(av, bp, ao, 0, 0, 0);
            }
            short4_t w;
#pragma unroll
            for (int gg = 0; gg < 4; ++gg) w[gg] = (short)f2b(ao[gg]);
            *(short4_t*)&qL[iRow * 136 + hc + lq * 4] = w;
        }
    }
    __syncthreads();

    // ---- P4: O-proj + resid + LN -> xre, xL ----
    mm_g<4, 2, 128>(qL, 136, wt + OFFO(0), wv * 32, lane, a2);
    add_bias<4, 2>(a2, bo0, wv * 32, l15);
    add_resid_reg<4, 2>(a2, xre);
    ln_norm<4, 2>(a2, redL, l1s0, l1b0, wv * 32, l15, lq, wv);
    save_resid<4, 2>(xre, a2);
    st_n<4, 2>(a2, xL, 136, wv * 32, l15, lq);
    __syncthreads();

    // ---- P5: FFN W1 + relu -> hL ----
    {
        floatx4 a4[4][4];
        mm_g<4, 4, 128>(xL, 136, wt + OFFW1(0), wv * 64, lane, a4);
        add_bias<4, 4>(a4, b10, wv * 64, l15);
#pragma unroll
        for (int r = 0; r < 4; ++r)
#pragma unroll
            for (int c = 0; c < 4; ++c)
#pragma unroll
                for (int gg = 0; gg < 4; ++gg) a4[r][c][gg] = fmaxf(a4[r][c][gg], 0.f);
        st_n<4, 4>(a4, hL, 272, wv * 64, l15, lq);
    }
    __syncthreads();

    // ---- P6: FFN W2 + resid + LN -> xre, xL; row0 -> xr0f (fp32) ----
    mm_g<4, 2, 256>(hL, 272, wt + OFFW2(0), wv * 32, lane, a2);
    add_bias<4, 2>(a2, b20, wv * 32, l15);
    add_resid_reg<4, 2>(a2, xre);
    ln_norm<4, 2>(a2, redL, l2s0, l2b0, wv * 32, l15, lq, wv);
    save_resid<4, 2>(xre, a2);
    st_n<4, 2>(a2, xL, 136, wv * 32, l15, lq);
    if (lq == 0) {
#pragma unroll
        for (int c = 0; c < 2; ++c)
            xr0f[(size_t)gid * 128 + wv * 32 + c * 16 + l15] = a2[0][c][0];   // row 0
    }
    __syncthreads();

    // ---- P7: L1 K,V (full) + q at t=0 ----
    mm_g<4, 2, 128>(xL, 136, wt + OFFK(1), wv * 32, lane, a2);
    add_bias<4, 2>(a2, bk1, wv * 32, l15);
    st_n<4, 2>(a2, kL, 136, wv * 32, l15, lq);
    mm_g<4, 2, 128>(xL, 136, wt + OFFV(1), wv * 32, lane, a2);
    add_bias<4, 2>(a2, bv1, wv * 32, l15);
    st_t<4, 2>(a2, vT, 68, wv * 32, l15, lq);
    if (tid < 128) {
        int d = tid;
        float a = bq1[d];
        const ushort_t* wq = wt + OFFQ(1) + d * 128;
#pragma unroll 4
        for (int j0 = 0; j0 < 128; j0 += 8) {
            short8 w8 = *(const short8*)&wq[j0];
            short8 x8 = *(const short8*)&xL[j0];
#pragma unroll
            for (int q = 0; q < 8; ++q)
                a = fmaf(b2f((ushort_t)x8[q]), b2f((ushort_t)w8[q]), a);
        }
        q1L[d] = a;
    }
    __syncthreads();

    // ---- P8: L1 single-query attention -> o1 ----
    {
        int h = tid >> 5, jj = tid & 31;
        int hc = h * 16;
        float s[2];
#pragma unroll
        for (int half = 0; half < 2; ++half) {
            int j = jj + half * 32;
            float a = 0.f;
            short8 k0v = *(const short8*)&kL[j * 136 + hc];
            short8 k1v = *(const short8*)&kL[j * 136 + hc + 8];
#pragma unroll
            for (int q = 0; q < 8; ++q) {
                a = fmaf(q1L[hc + q], b2f((ushort_t)k0v[q]), a);
                a = fmaf(q1L[hc + 8 + q], b2f((ushort_t)k1v[q]), a);
            }
            s[half] = (j < len) ? a * SCALEQK : -1e9f;
        }
        float mx = fmaxf(s[0], s[1]);
#pragma unroll
        for (int d = 1; d < 32; d <<= 1) mx = fmaxf(mx, __shfl_xor(mx, d));
        float e0 = __expf(s[0] - mx), e1 = __expf(s[1] - mx);
        float sum = e0 + e1;
#pragma unroll
        for (int d = 1; d < 32; d <<= 1) sum += __shfl_xor(sum, d);
        float inv = 1.f / sum;
        psL[h * 68 + jj] = e0 * inv;
        psL[h * 68 + jj + 32] = e1 * inv;
    }
    __syncthreads();
    if (tid < 128) {
        int h = tid >> 4, d = tid & 15, hc = h * 16;
        float a = 0.f;
#pragma unroll 4
        for (int j0 = 0; j0 < 64; j0 += 4) {
            float4 p4 = *(const float4*)&psL[h * 68 + j0];
            short4_t v4 = *(const short4_t*)&vT[(hc + d) * 68 + j0];
            a += p4.x * b2f((ushort_t)v4[0]) + p4.y * b2f((ushort_t)v4[1])
               + p4.z * b2f((ushort_t)v4[2]) + p4.w * b2f((ushort_t)v4[3]);
        }
        o1[(size_t)gid * 128 + hc + d] = f2b(a);
    }
}

// ---------------------------------------------------------------------------
// K2 v2: fused tail, 1024 threads (16 waves = 4 waves/SIMD) for latency
// hiding. One block per spatial group b: 128 rows x 128 cols in LDS.
// GEMM: wave (wr,wc) = (wv>>2, wv&3): rows wr*32 (RT=2), cols wc*32 (CT=2).
// Attention: wave = (head wv&7, i-half wv>>3), 4 x 16-row units each.
// ---------------------------------------------------------------------------
__global__ __launch_bounds__(1024, 1) void k2_mega(
    const ushort_t* __restrict__ o1, const float* __restrict__ xr0f,
    const int* __restrict__ lens, const ushort_t* __restrict__ wt,
    const float* __restrict__ bq, const float* __restrict__ bk,
    const float* __restrict__ bv, const float* __restrict__ bo,
    const float* __restrict__ l1s, const float* __restrict__ l1b,
    const float* __restrict__ b1, const float* __restrict__ b2,
    const float* __restrict__ l2s, const float* __restrict__ l2b,
    float* __restrict__ outp)
{
    __shared__ ushort_t pool[69632];    // 139264 B
    __shared__ float redL[1024];
    __shared__ int vldL[128];
    ushort_t* xL = pool;                // [128][136]
    ushort_t* qL = pool + 17408;        // [128][136] (attn o written in place)
    ushort_t* kL = pool + 34816;        // [128][136]
    ushort_t* vT = pool + 52224;        // [128][136] v transposed (d-major)
    ushort_t* hL = pool + 34816;        // [128][272] FFN hidden, overlays kL+vT

    const int tid = threadIdx.x, lane = tid & 63, wv = tid >> 6;
    const int l15 = lane & 15, lq = lane >> 4;
    const int wc = wv & 3, wr = wv >> 2;       // GEMM wave grid
    const int cb2 = wc * 32, cb4 = wc * 64, rb = wr * 32;
    const int b = blockIdx.x;
    const size_t rowg = (size_t)b * 128;

    // ---- stage o1 -> xL (bf16 copy) + validity ----
#pragma unroll
    for (int it = 0; it < 2; ++it) {
        int e8 = tid + it * 1024;
        int row = e8 >> 4, kg = e8 & 15;
        *(short8*)&xL[row * 136 + kg * 8] = *(const short8*)&o1[(rowg + row) * 128 + kg * 8];
    }
    if (tid < 128) vldL[tid] = (lens[b * 128 + tid] > 0) ? 1 : 0;
    __syncthreads();

    // per-lane j-validity mask: bit jt*4+g <-> j = jt*16 + lq*4 + g
    unsigned jm = 0;
#pragma unroll
    for (int jt = 0; jt < 8; ++jt)
#pragma unroll
        for (int g = 0; g < 4; ++g)
            if (vldL[jt * 16 + lq * 4 + g]) jm |= (1u << (jt * 4 + g));

    // residual stream (fp32, this thread's slice) seeded from xr0f
    float xre[2][2][4];
#pragma unroll
    for (int r = 0; r < 2; ++r)
#pragma unroll
        for (int c = 0; c < 2; ++c)
#pragma unroll
            for (int g = 0; g < 4; ++g)
                xre[r][c][g] = xr0f[(rowg + rb + r * 16 + lq * 4 + g) * 128 + cb2 + c * 16 + l15];

    floatx4 a2[2][2];

    for (int l = 1; l < 4; ++l) {
        if (l >= 2) {
            // ---- QKV ----
            mm_g<2, 2, 128>(xL + rb * 136, 136, wt + OFFQ(l), cb2, lane, a2);
            add_bias<2, 2>(a2, bq + l * H_, cb2, l15);
            st_n<2, 2>(a2, qL + rb * 136, 136, cb2, l15, lq);
            mm_g<2, 2, 128>(xL + rb * 136, 136, wt + OFFK(l), cb2, lane, a2);
            add_bias<2, 2>(a2, bk + l * H_, cb2, l15);
            st_n<2, 2>(a2, kL + rb * 136, 136, cb2, l15, lq);
            mm_g<2, 2, 128>(xL + rb * 136, 136, wt + OFFV(l), cb2, lane, a2);
            add_bias<2, 2>(a2, bv + l * H_, cb2, l15);
            st_t<2, 2>(a2, vT + rb, 136, cb2, l15, lq);
            __syncthreads();
            // ---- spatial attention: wave = (head, i-half); 4 x 16-row units ----
            {
                const int h = wv & 7, hc = h * 16, ihalf = wv >> 3;
                for (int u = 0; u < 4; ++u) {
                    const int iRow = ihalf * 64 + u * 16 + l15;
                    const bool iv = vldL[iRow] != 0;
                    short8 z8 = {0, 0, 0, 0, 0, 0, 0, 0};
                    short8 bqf = z8;
                    if (lq < 2) bqf = *(const short8*)&qL[iRow * 136 + hc + lq * 8];
                    floatx4 st[8];
#pragma unroll
                    for (int jt = 0; jt < 8; ++jt) {
                        short8 ak = z8;
                        if (lq < 2) ak = *(const short8*)&kL[(jt * 16 + l15) * 136 + hc + lq * 8];
                        floatx4 zz = {0.f, 0.f, 0.f, 0.f};
                        st[jt] = __builtin_amdgcn_mfma_f32_16x16x32_bf16(ak, bqf, zz, 0, 0, 0);
                    }
                    int px[8][2];
                    softmax_pack<8>(st, iv, jm, px);
                    floatx4 ao = {0.f, 0.f, 0.f, 0.f};
#pragma unroll
                    for (int jc = 0; jc < 4; ++jc) {
                        short8 av = vfrag(vT, 136, hc + l15, jc * 32 + lq * 8);
                        short8 bp = pfrag(px, jc, lq, l15);
                        ao = __builtin_amdgcn_mfma_f32_16x16x32_bf16(av, bp, ao, 0, 0, 0);
                    }
                    short4_t w;
#pragma unroll
                    for (int g = 0; g < 4; ++g) w[g] = (short)f2b(ao[g]);
                    *(short4_t*)&qL[iRow * 136 + hc + lq * 4] = w;
                }
            }
            __syncthreads();
        }

        // ---- O-proj + resid + LN -> xre, xL ----
        const ushort_t* aIn = ((l == 1) ? xL : qL) + rb * 136;
        mm_g<2, 2, 128>(aIn, 136, wt + OFFO(l), cb2, lane, a2);
        add_bias<2, 2>(a2, bo + l * H_, cb2, l15);
        add_resid_reg<2, 2>(a2, xre);
        ln_normW<2, 2>(a2, redL, l1s + l * H_, l1b + l * H_, cb2, rb, l15, lq, wc);
        save_resid<2, 2>(xre, a2);
        st_n<2, 2>(a2, xL + rb * 136, 136, cb2, l15, lq);
        __syncthreads();

        // ---- FFN W1 + relu -> hL ----
        {
            floatx4 a4[2][4];
            mm_g<2, 4, 128>(xL + rb * 136, 136, wt + OFFW1(l), cb4, lane, a4);
            add_bias<2, 4>(a4, b1 + l * FF_, cb4, l15);
#pragma unroll
            for (int r = 0; r < 2; ++r)
#pragma unroll
                for (int c = 0; c < 4; ++c)
#pragma unroll
                    for (int g = 0; g < 4; ++g) a4[r][c][g] = fmaxf(a4[r][c][g], 0.f);
            st_n<2, 4>(a4, hL + rb * 272, 272, cb4, l15, lq);
        }
        __syncthreads();

        // ---- FFN W2 + resid + LN ----
        mm_g<2, 2, 256>(hL + rb * 272, 272, wt + OFFW2(l), cb2, lane, a2);
        add_bias<2, 2>(a2, b2 + l * H_, cb2, l15);
        add_resid_reg<2, 2>(a2, xre);
        ln_normW<2, 2>(a2, redL, l2s + l * H_, l2b + l * H_, cb2, rb, l15, lq, wc);
        if (l == 3) {
            // final: rows s<64 -> out[b][s][col] fp32
            if (wr < 2) {
#pragma unroll
                for (int r = 0; r < 2; ++r)
#pragma unroll
                    for (int c = 0; c < 2; ++c)
#pragma unroll
                        for (int g = 0; g < 4; ++g) {
                            int row = rb + r * 16 + lq * 4 + g;
                            outp[((size_t)(b * 64 + row)) * 128 + cb2 + c * 16 + l15] = a2[r][c][g];
                        }
            }
        } else {
            save_resid<2, 2>(xre, a2);
            st_n<2, 2>(a2, xL + rb * 136, 136, cb2, l15, lq);
            __syncthreads();
        }
    }
}

// ---------------------------------------------------------------------------
extern "C" void kernel_launch(void* const* d_in, const int* in_sizes, int n_in,
                              void* d_out, int out_size, void* d_ws, size_t ws_size,
                              hipStream_t stream)
{
    const float* poly   = (const float*)d_in[0];
    const int*   lens   = (const int*)d_in[1];
    const float* proj_w = (const float*)d_in[2];
    const float* proj_b = (const float*)d_in[3];
    const float* pls    = (const float*)d_in[4];
    const float* plb    = (const float*)d_in[5];
    const float* pos    = (const float*)d_in[6];
    const float* Wq = (const float*)d_in[7];
    const float* bq = (const float*)d_in[8];
    const float* Wk = (const float*)d_in[9];
    const float* bk = (const float*)d_in[10];
    const float* Wv = (const float*)d_in[11];
    const float* bv = (const float*)d_in[12];
    const float* Wo = (const float*)d_in[13];
    const float* bo = (const float*)d_in[14];
    const float* l1s = (const float*)d_in[15];
    const float* l1b = (const float*)d_in[16];
    const float* W1 = (const float*)d_in[17];
    const float* b1 = (const float*)d_in[18];
    const float* W2 = (const float*)d_in[19];
    const float* b2 = (const float*)d_in[20];
    const float* l2s = (const float*)d_in[21];
    const float* l2b = (const float*)d_in[22];
    float* outp = (float*)d_out;

    char* base = (char*)d_ws;
    ushort_t* wt    = (ushort_t*)base;                 // 540672 bf16 = 1,081,344 B
    ushort_t* o1buf = (ushort_t*)(base + 1081344);     // [2048][128] bf16
    float* xr0f     = (float*)(base + 1605632);        // [2048][128] fp32

    const int HH = H_ * H_, HF = H_ * FF_;
    WtArgs wa;
    wa.e[0] = {proj_w, 128, 128, 2, OFFP};
    for (int l = 0; l < 4; ++l) {
        wa.e[1 + l * 4 + 0] = {Wq + l * HH, 128, 128, 2, OFFQ(l)};
        wa.e[1 + l * 4 + 1] = {Wk + l * HH, 128, 128, 2, OFFK(l)};
        wa.e[1 + l * 4 + 2] = {Wv + l * HH, 128, 128, 2, OFFV(l)};
        wa.e[1 + l * 4 + 3] = {Wo + l * HH, 128, 128, 2, OFFO(l)};
    }
    for (int l = 0; l < 4; ++l) {
        wa.e[17 + l * 2 + 0] = {W1 + l * HF, 256, 128, 3, OFFW1(l)};
        wa.e[17 + l * 2 + 1] = {W2 + l * HF, 128, 256, 2, OFFW2(l)};
    }
    wt_kernel<<<dim3(25, 32), 256, 0, stream>>>(wa, wt);

    // ---- fused input-proj + L0 + L1(kv,q,attn) ----
    k1_mega<<<dim3(2048), 256, 0, stream>>>(
        poly, lens, wt,
        proj_b, pls, plb, pos,
        bq, bk, bv, bo, l1s, l1b, b1, b2, l2s, l2b,
        bq + H_, bk + H_, bv + H_,
        o1buf, xr0f);

    // ---- fused tail: L1 O-proj/FFN + spatial layers 2,3 + final store ----
    k2_mega<<<dim3(16), 1024, 0, stream>>>(
        o1buf, xr0f, lens, wt,
        bq, bk, bv, bo, l1s, l1b, b1, b2, l2s, l2b,
        outp);
}

// Round 4
// 385.544 us; speedup vs baseline: 1.2309x; 1.2163x over previous
//
#include <hip/hip_runtime.h>

typedef short short8 __attribute__((ext_vector_type(8)));
typedef short short4_t __attribute__((ext_vector_type(4)));
typedef float floatx4 __attribute__((ext_vector_type(4)));
typedef unsigned short ushort_t;

#define B_ 16
#define S_ 128
#define T_ 64
#define H_ 128
#define FF_ 256
#define SCALEQK 0.25f

// bf16 transposed-weight pool offsets (ushort units)
#define OFFP 0
#define OFFQ(l) (16384 + (l) * 65536)
#define OFFK(l) (OFFQ(l) + 16384)
#define OFFV(l) (OFFQ(l) + 32768)
#define OFFO(l) (OFFQ(l) + 49152)
#define OFFW1(l) (278528 + (l) * 65536)
#define OFFW2(l) (OFFW1(l) + 32768)

__device__ __forceinline__ float b2f(ushort_t u) {
    union { unsigned int i; float f; } x; x.i = ((unsigned int)u) << 16; return x.f;
}
__device__ __forceinline__ ushort_t f2b(float f) {
    union { float f; unsigned int i; } x; x.f = f;
    unsigned int r = x.i + 0x7fffu + ((x.i >> 16) & 1u);
    return (ushort_t)(r >> 16);
}
__device__ __forceinline__ int pack2b(float a, float b) {
    return (int)f2b(a) | ((int)f2b(b) << 16);
}

// ---------------------------------------------------------------------------
// Weight preconvert: fp32 W[K][N] -> bf16 wT[N][K] (round-2 proven).
// ---------------------------------------------------------------------------
struct WtEnt { const float* src; int N; int K; int nclog2; int dstoff; };
struct WtArgs { WtEnt e[25]; };

__global__ __launch_bounds__(256) void wt_kernel(WtArgs a, ushort_t* __restrict__ dst) {
    WtEnt ent = a.e[blockIdx.x];
    const int tiles_c = ent.N >> 5;
    const int nt = (ent.K >> 5) * tiles_c;
    const int t = blockIdx.y;
    if (t >= nt) return;
    const int tc = t & (tiles_c - 1);
    const int tr = t >> ent.nclog2;
    __shared__ float ld[32 * 33];
    const int tid = threadIdx.x;
#pragma unroll
    for (int i = 0; i < 4; ++i) {
        int e = tid + i * 256;
        int rr = e >> 5, cc = e & 31;
        ld[rr * 33 + cc] = ent.src[(tr * 32 + rr) * ent.N + tc * 32 + cc];
    }
    __syncthreads();
    ushort_t* d = dst + ent.dstoff;
#pragma unroll
    for (int i = 0; i < 4; ++i) {
        int e = tid + i * 256;
        int rr = e >> 5, cc = e & 31;
        d[(tc * 32 + rr) * ent.K + tr * 32 + cc] = f2b(ld[cc * 33 + rr]);
    }
}

// ---------------------------------------------------------------------------
// Proven helpers (templates generic in RT/CT/JT).
// ---------------------------------------------------------------------------
template<int RT, int CT, int KK>
__device__ __forceinline__ void mm_g(const ushort_t* aL, int sa,
                                     const ushort_t* __restrict__ wT,
                                     int colbase, int lane, floatx4 (&acc)[RT][CT]) {
    const int l15 = lane & 15, lq8 = (lane >> 4) * 8;
#pragma unroll
    for (int r = 0; r < RT; ++r)
#pragma unroll
        for (int c = 0; c < CT; ++c) acc[r][c] = (floatx4){0.f, 0.f, 0.f, 0.f};
#pragma unroll
    for (int k0 = 0; k0 < KK; k0 += 32) {
        short8 b[CT];
#pragma unroll
        for (int c = 0; c < CT; ++c)
            b[c] = *(const short8*)&wT[(colbase + c * 16 + l15) * KK + k0 + lq8];
#pragma unroll
        for (int r = 0; r < RT; ++r) {
            short8 a = *(const short8*)&aL[(r * 16 + l15) * sa + k0 + lq8];
#pragma unroll
            for (int c = 0; c < CT; ++c)
                acc[r][c] = __builtin_amdgcn_mfma_f32_16x16x32_bf16(a, b[c], acc[r][c], 0, 0, 0);
        }
    }
}

template<int RT, int CT>
__device__ __forceinline__ void add_bias(floatx4 (&acc)[RT][CT], const float* b,
                                         int colbase, int l15) {
#pragma unroll
    for (int c = 0; c < CT; ++c) {
        float bc = b[colbase + c * 16 + l15];
#pragma unroll
        for (int r = 0; r < RT; ++r)
#pragma unroll
            for (int g = 0; g < 4; ++g) acc[r][c][g] += bc;
    }
}

template<int RT, int CT>
__device__ __forceinline__ void add_resid_reg(floatx4 (&acc)[RT][CT],
                                              const float (&res)[RT][CT][4]) {
#pragma unroll
    for (int r = 0; r < RT; ++r)
#pragma unroll
        for (int c = 0; c < CT; ++c)
#pragma unroll
            for (int g = 0; g < 4; ++g) acc[r][c][g] += res[r][c][g];
}
template<int RT, int CT>
__device__ __forceinline__ void save_resid(float (&res)[RT][CT][4],
                                           const floatx4 (&acc)[RT][CT]) {
#pragma unroll
    for (int r = 0; r < RT; ++r)
#pragma unroll
        for (int c = 0; c < CT; ++c)
#pragma unroll
            for (int g = 0; g < 4; ++g) res[r][c][g] = acc[r][c][g];
}

template<int RT, int CT>
__device__ __forceinline__ void st_n(const floatx4 (&acc)[RT][CT], ushort_t* dst, int stride,
                                     int colbase, int l15, int lq) {
#pragma unroll
    for (int r = 0; r < RT; ++r)
#pragma unroll
        for (int g = 0; g < 4; ++g) {
            int row = r * 16 + lq * 4 + g;
#pragma unroll
            for (int c = 0; c < CT; ++c)
                dst[row * stride + colbase + c * 16 + l15] = f2b(acc[r][c][g]);
        }
}

template<int RT, int CT>
__device__ __forceinline__ void st_t(const floatx4 (&acc)[RT][CT], ushort_t* dst, int stride,
                                     int colbase, int l15, int lq) {
#pragma unroll
    for (int r = 0; r < RT; ++r)
#pragma unroll
        for (int c = 0; c < CT; ++c) {
            int d = colbase + c * 16 + l15;
            short4_t p;
#pragma unroll
            for (int g = 0; g < 4; ++g) p[g] = (short)f2b(acc[r][c][g]);
            *(short4_t*)&dst[d * stride + r * 16 + lq * 4] = p;
        }
}

// 4 col-waves over 64 rows (wv = col-wave index)
template<int RT, int CT>
__device__ __forceinline__ void ln_norm(floatx4 (&acc)[RT][CT], float* redL,
                                        const float* lns, const float* lnb,
                                        int colbase, int l15, int lq, int wv) {
#pragma unroll
    for (int r = 0; r < RT; ++r)
#pragma unroll
        for (int g = 0; g < 4; ++g) {
            float s = 0.f, q = 0.f;
#pragma unroll
            for (int c = 0; c < CT; ++c) { float v = acc[r][c][g]; s += v; q += v * v; }
            s += __shfl_xor(s, 1); s += __shfl_xor(s, 2); s += __shfl_xor(s, 4); s += __shfl_xor(s, 8);
            q += __shfl_xor(q, 1); q += __shfl_xor(q, 2); q += __shfl_xor(q, 4); q += __shfl_xor(q, 8);
            if (l15 == 0) {
                int row = r * 16 + lq * 4 + g;
                redL[row * 8 + wv] = s;
                redL[row * 8 + 4 + wv] = q;
            }
        }
    __syncthreads();
#pragma unroll
    for (int r = 0; r < RT; ++r)
#pragma unroll
        for (int g = 0; g < 4; ++g) {
            int row = r * 16 + lq * 4 + g;
            float4 S = *(float4*)&redL[row * 8];
            float4 Q = *(float4*)&redL[row * 8 + 4];
            float mean = (S.x + S.y + S.z + S.w) * (1.f / 128.f);
            float var = (Q.x + Q.y + Q.z + Q.w) * (1.f / 128.f) - mean * mean;
            float rstd = rsqrtf(var + 1e-5f);
#pragma unroll
            for (int c = 0; c < CT; ++c) {
                int col = colbase + c * 16 + l15;
                acc[r][c][g] = (acc[r][c][g] - mean) * rstd * lns[col] + lnb[col];
            }
        }
}

template<int JT>
__device__ __forceinline__ void softmax_pack(floatx4 (&st)[JT], bool iv, unsigned jm,
                                             int (&px)[JT][2]) {
    float ev[JT][4];
    float mx = -3.0e38f;
#pragma unroll
    for (int jt = 0; jt < JT; ++jt)
#pragma unroll
        for (int g = 0; g < 4; ++g) {
            bool ok = iv && ((jm >> (jt * 4 + g)) & 1u);
            float s = ok ? st[jt][g] * SCALEQK : -1e9f;
            ev[jt][g] = s; mx = fmaxf(mx, s);
        }
    mx = fmaxf(mx, __shfl_xor(mx, 16)); mx = fmaxf(mx, __shfl_xor(mx, 32));
    float sum = 0.f;
#pragma unroll
    for (int jt = 0; jt < JT; ++jt)
#pragma unroll
        for (int g = 0; g < 4; ++g) { float e = __expf(ev[jt][g] - mx); ev[jt][g] = e; sum += e; }
    sum += __shfl_xor(sum, 16); sum += __shfl_xor(sum, 32);
    float inv = 1.f / sum;
#pragma unroll
    for (int jt = 0; jt < JT; ++jt) {
        px[jt][0] = pack2b(ev[jt][0] * inv, ev[jt][1] * inv);
        px[jt][1] = pack2b(ev[jt][2] * inv, ev[jt][3] * inv);
    }
}

__device__ __forceinline__ short8 pfrag(const int (*px)[2], int jc, int lq, int l15) {
    const int jA = (lq & 1) * 32 + l15;
    int a0 = __shfl(px[jc * 2][0], jA);
    int a1 = __shfl(px[jc * 2][1], jA);
    int a2 = __shfl(px[jc * 2][0], jA + 16);
    int a3 = __shfl(px[jc * 2][1], jA + 16);
    int b0 = __shfl(px[jc * 2 + 1][0], jA);
    int b1 = __shfl(px[jc * 2 + 1][1], jA);
    int b2 = __shfl(px[jc * 2 + 1][0], jA + 16);
    int b3 = __shfl(px[jc * 2 + 1][1], jA + 16);
    const bool t = (lq >> 1) != 0;
    union { int4 i; short8 s; } u;
    u.i = make_int4(t ? b0 : a0, t ? b1 : a1, t ? b2 : a2, t ? b3 : a3);
    return u.s;
}
__device__ __forceinline__ short8 vfrag(const ushort_t* vT, int stride, int row, int off) {
    int2 a = *(const int2*)&vT[row * stride + off];
    int2 b = *(const int2*)&vT[row * stride + off + 4];
    union { int4 i; short8 s; } u;
    u.i = make_int4(a.x, a.y, b.x, b.y);
    return u.s;
}

// ---------------------------------------------------------------------------
// K1 (round-5 proven, verbatim): per group gid (64 rows): input proj -> L0
// full -> L1 (kv + q@t0 + attn). Writes o1[gid][128] bf16 + xr0f[gid][128]
// fp32. 2048 blocks x 256 thr.
// ---------------------------------------------------------------------------
__global__ __launch_bounds__(256, 2) void k1_mega(
    const float* __restrict__ poly, const int* __restrict__ lens,
    const ushort_t* __restrict__ wt,
    const float* __restrict__ projb, const float* __restrict__ pls,
    const float* __restrict__ plb, const float* __restrict__ pos,
    const float* __restrict__ bq0, const float* __restrict__ bk0,
    const float* __restrict__ bv0, const float* __restrict__ bo0,
    const float* __restrict__ l1s0, const float* __restrict__ l1b0,
    const float* __restrict__ b10, const float* __restrict__ b20,
    const float* __restrict__ l2s0, const float* __restrict__ l2b0,
    const float* __restrict__ bq1, const float* __restrict__ bk1,
    const float* __restrict__ bv1,
    ushort_t* __restrict__ o1, float* __restrict__ xr0f)
{
    __shared__ ushort_t pool[34816];
    __shared__ float redL[512];
    __shared__ float psL[8 * 68];
    __shared__ float q1L[128];
    ushort_t* xL = pool;            // [64][136]
    ushort_t* qL = pool + 8704;     // [64][136]  (o written in-place per head)
    ushort_t* kL = pool + 17408;    // [64][136]
    ushort_t* vT = pool + 26112;    // [128][68]  v transposed
    ushort_t* hL = pool + 17408;    // [64][272]  FFN hidden, overlays kL+vT

    const int tid = threadIdx.x, lane = tid & 63, wv = tid >> 6;
    const int l15 = lane & 15, lq = lane >> 4;
    const int gid = blockIdx.x;
    const int len = lens[gid];

    // ---- stage poly -> xL (bf16, -1 pad) ----
    {
        const float* pg = poly + (size_t)gid * 8192;
#pragma unroll
        for (int it = 0; it < 8; ++it) {
            int e4 = (tid + it * 256) * 4;
            int row = e4 >> 7, col = e4 & 127;
            float4 f = *(const float4*)(pg + e4);
            if (row >= len) { f.x = -1.f; f.y = -1.f; f.z = -1.f; f.w = -1.f; }
            short4_t u;
            u[0] = (short)f2b(f.x); u[1] = (short)f2b(f.y);
            u[2] = (short)f2b(f.z); u[3] = (short)f2b(f.w);
            *(short4_t*)&xL[row * 136 + col] = u;
        }
    }
    __syncthreads();

    floatx4 a2[4][2];
    float xre[4][2][4];             // fp32 residual stream (this thread's slice)

    // ---- P1: input proj + LN + relu + pos -> xre, xL ----
    mm_g<4, 2, 128>(xL, 136, wt + OFFP, wv * 32, lane, a2);
    add_bias<4, 2>(a2, projb, wv * 32, l15);
    ln_norm<4, 2>(a2, redL, pls, plb, wv * 32, l15, lq, wv);
    __syncthreads();               // done reading xL (staged poly) before overwrite
#pragma unroll
    for (int r = 0; r < 4; ++r)
#pragma unroll
        for (int gg = 0; gg < 4; ++gg) {
            int row = r * 16 + lq * 4 + gg;
#pragma unroll
            for (int c = 0; c < 2; ++c) {
                int col = wv * 32 + c * 16 + l15;
                float v = fmaxf(a2[r][c][gg], 0.f) + pos[row * 128 + col];
                xre[r][c][gg] = v;
                xL[row * 136 + col] = f2b(v);
            }
        }
    __syncthreads();

    // ---- P2: L0 QKV ----
    mm_g<4, 2, 128>(xL, 136, wt + OFFQ(0), wv * 32, lane, a2);
    add_bias<4, 2>(a2, bq0, wv * 32, l15);
    st_n<4, 2>(a2, qL, 136, wv * 32, l15, lq);
    mm_g<4, 2, 128>(xL, 136, wt + OFFK(0), wv * 32, lane, a2);
    add_bias<4, 2>(a2, bk0, wv * 32, l15);
    st_n<4, 2>(a2, kL, 136, wv * 32, l15, lq);
    mm_g<4, 2, 128>(xL, 136, wt + OFFV(0), wv * 32, lane, a2);
    add_bias<4, 2>(a2, bv0, wv * 32, l15);
    st_t<4, 2>(a2, vT, 68, wv * 32, l15, lq);
    __syncthreads();

    // ---- P3: L0 attention (MFMA S^T, reg softmax, shuffle-PV) ----
    {
        const int iRow = wv * 16 + l15;
        const bool iv = iRow < len;
        unsigned jm = 0;
#pragma unroll
        for (int jt = 0; jt < 4; ++jt)
#pragma unroll
            for (int gg = 0; gg < 4; ++gg)
                if (jt * 16 + lq * 4 + gg < len) jm |= (1u << (jt * 4 + gg));
        for (int h = 0; h < 8; ++h) {
            const int hc = h * 16;
            short8 z8 = {0, 0, 0, 0, 0, 0, 0, 0};
            short8 bqf = z8;
            if (lq < 2) bqf = *(const short8*)&qL[iRow * 136 + hc + lq * 8];
            floatx4 st[4];
#pragma unroll
            for (int jt = 0; jt < 4; ++jt) {
                short8 ak = z8;
                if (lq < 2) ak = *(const short8*)&kL[(jt * 16 + l15) * 136 + hc + lq * 8];
                floatx4 zz = {0.f, 0.f, 0.f, 0.f};
                st[jt] = __builtin_amdgcn_mfma_f32_16x16x32_bf16(ak, bqf, zz, 0, 0, 0);
            }
            int px[4][2];
            softmax_pack<4>(st, iv, jm, px);
            floatx4 ao = {0.f, 0.f, 0.f, 0.f};
#pragma unroll
            for (int jc = 0; jc < 2; ++jc) {
                short8 av = vfrag(vT, 68, hc + l15, jc * 32 + lq * 8);
                short8 bp = pfrag(px, jc, lq, l15);
                ao = __builtin_amdgcn_mfma_f32_16x16x32_bf16(av, bp, ao, 0, 0, 0);
            }
            short4_t w;
#pragma unroll
            for (int gg = 0; gg < 4; ++gg) w[gg] = (short)f2b(ao[gg]);
            *(short4_t*)&qL[iRow * 136 + hc + lq * 4] = w;
        }
    }
    __syncthreads();

    // ---- P4: O-proj + resid + LN -> xre, xL ----
    mm_g<4, 2, 128>(qL, 136, wt + OFFO(0), wv * 32, lane, a2);
    add_bias<4, 2>(a2, bo0, wv * 32, l15);
    add_resid_reg<4, 2>(a2, xre);
    ln_norm<4, 2>(a2, redL, l1s0, l1b0, wv * 32, l15, lq, wv);
    save_resid<4, 2>(xre, a2);
    st_n<4, 2>(a2, xL, 136, wv * 32, l15, lq);
    __syncthreads();

    // ---- P5: FFN W1 + relu -> hL ----
    {
        floatx4 a4[4][4];
        mm_g<4, 4, 128>(xL, 136, wt + OFFW1(0), wv * 64, lane, a4);
        add_bias<4, 4>(a4, b10, wv * 64, l15);
#pragma unroll
        for (int r = 0; r < 4; ++r)
#pragma unroll
            for (int c = 0; c < 4; ++c)
#pragma unroll
                for (int gg = 0; gg < 4; ++gg) a4[r][c][gg] = fmaxf(a4[r][c][gg], 0.f);
        st_n<4, 4>(a4, hL, 272, wv * 64, l15, lq);
    }
    __syncthreads();

    // ---- P6: FFN W2 + resid + LN -> xre, xL; row0 -> xr0f (fp32) ----
    mm_g<4, 2, 256>(hL, 272, wt + OFFW2(0), wv * 32, lane, a2);
    add_bias<4, 2>(a2, b20, wv * 32, l15);
    add_resid_reg<4, 2>(a2, xre);
    ln_norm<4, 2>(a2, redL, l2s0, l2b0, wv * 32, l15, lq, wv);
    save_resid<4, 2>(xre, a2);
    st_n<4, 2>(a2, xL, 136, wv * 32, l15, lq);
    if (lq == 0) {
#pragma unroll
        for (int c = 0; c < 2; ++c)
            xr0f[(size_t)gid * 128 + wv * 32 + c * 16 + l15] = a2[0][c][0];   // row 0
    }
    __syncthreads();

    // ---- P7: L1 K,V (full) + q at t=0 ----
    mm_g<4, 2, 128>(xL, 136, wt + OFFK(1), wv * 32, lane, a2);
    add_bias<4, 2>(a2, bk1, wv * 32, l15);
    st_n<4, 2>(a2, kL, 136, wv * 32, l15, lq);
    mm_g<4, 2, 128>(xL, 136, wt + OFFV(1), wv * 32, lane, a2);
    add_bias<4, 2>(a2, bv1, wv * 32, l15);
    st_t<4, 2>(a2, vT, 68, wv * 32, l15, lq);
    if (tid < 128) {
        int d = tid;
        float a = bq1[d];
        const ushort_t* wq = wt + OFFQ(1) + d * 128;
#pragma unroll 4
        for (int j0 = 0; j0 < 128; j0 += 8) {
            short8 w8 = *(const short8*)&wq[j0];
            short8 x8 = *(const short8*)&xL[j0];
#pragma unroll
            for (int q = 0; q < 8; ++q)
                a = fmaf(b2f((ushort_t)x8[q]), b2f((ushort_t)w8[q]), a);
        }
        q1L[d] = a;
    }
    __syncthreads();

    // ---- P8: L1 single-query attention -> o1 ----
    {
        int h = tid >> 5, jj = tid & 31;
        int hc = h * 16;
        float s[2];
#pragma unroll
        for (int half = 0; half < 2; ++half) {
            int j = jj + half * 32;
            float a = 0.f;
            short8 k0v = *(const short8*)&kL[j * 136 + hc];
            short8 k1v = *(const short8*)&kL[j * 136 + hc + 8];
#pragma unroll
            for (int q = 0; q < 8; ++q) {
                a = fmaf(q1L[hc + q], b2f((ushort_t)k0v[q]), a);
                a = fmaf(q1L[hc + 8 + q], b2f((ushort_t)k1v[q]), a);
            }
            s[half] = (j < len) ? a * SCALEQK : -1e9f;
        }
        float mx = fmaxf(s[0], s[1]);
#pragma unroll
        for (int d = 1; d < 32; d <<= 1) mx = fmaxf(mx, __shfl_xor(mx, d));
        float e0 = __expf(s[0] - mx), e1 = __expf(s[1] - mx);
        float sum = e0 + e1;
#pragma unroll
        for (int d = 1; d < 32; d <<= 1) sum += __shfl_xor(sum, d);
        float inv = 1.f / sum;
        psL[h * 68 + jj] = e0 * inv;
        psL[h * 68 + jj + 32] = e1 * inv;
    }
    __syncthreads();
    if (tid < 128) {
        int h = tid >> 4, d = tid & 15, hc = h * 16;
        float a = 0.f;
#pragma unroll 4
        for (int j0 = 0; j0 < 64; j0 += 4) {
            float4 p4 = *(const float4*)&psL[h * 68 + j0];
            short4_t v4 = *(const short4_t*)&vT[(hc + d) * 68 + j0];
            a += p4.x * b2f((ushort_t)v4[0]) + p4.y * b2f((ushort_t)v4[1])
               + p4.z * b2f((ushort_t)v4[2]) + p4.w * b2f((ushort_t)v4[3]);
        }
        o1[(size_t)gid * 128 + hc + d] = f2b(a);
    }
}

// ---------------------------------------------------------------------------
// K2A: spatial QKV + attention for one (group, head). Grid (16, 8) x 256 thr.
// Reads xg bf16 [2048][128]; writes attn-out slice aob[row][hc..hc+16) bf16.
// ---------------------------------------------------------------------------
__global__ __launch_bounds__(256, 3) void k2a(
    const ushort_t* __restrict__ xg, const int* __restrict__ lens,
    const ushort_t* __restrict__ wt, int l,
    const float* __restrict__ bq, const float* __restrict__ bk,
    const float* __restrict__ bv,
    ushort_t* __restrict__ aob)
{
    __shared__ ushort_t xL[128 * 136];
    __shared__ ushort_t qL[128 * 24];
    __shared__ ushort_t kL[128 * 24];
    __shared__ ushort_t vT[16 * 136];
    __shared__ int vldL[128];

    const int tid = threadIdx.x, lane = tid & 63, wv = tid >> 6;
    const int l15 = lane & 15, lq = lane >> 4;
    const int g = blockIdx.x, h = blockIdx.y, hc = h * 16;
    const size_t rowg = (size_t)g * 128;

    // stage x rows + validity
#pragma unroll
    for (int it = 0; it < 8; ++it) {
        int e8 = tid + it * 256;
        int row = e8 >> 4, kg = e8 & 15;
        *(short8*)&xL[row * 136 + kg * 8] = *(const short8*)&xg[(rowg + row) * 128 + kg * 8];
    }
    if (tid < 128) vldL[tid] = (lens[g * 128 + tid] > 0) ? 1 : 0;
    __syncthreads();

    unsigned jm = 0;
#pragma unroll
    for (int jt = 0; jt < 8; ++jt)
#pragma unroll
        for (int gg = 0; gg < 4; ++gg)
            if (vldL[jt * 16 + lq * 4 + gg]) jm |= (1u << (jt * 4 + gg));

    // QKV for this head: each wave does 32 rows (RT=2, CT=1, colbase=hc)
    {
        floatx4 a1[2][1];
        mm_g<2, 1, 128>(xL + (wv * 32) * 136, 136, wt + OFFQ(l), hc, lane, a1);
        add_bias<2, 1>(a1, bq, hc, l15);
        st_n<2, 1>(a1, qL + (wv * 32) * 24, 24, 0, l15, lq);
        mm_g<2, 1, 128>(xL + (wv * 32) * 136, 136, wt + OFFK(l), hc, lane, a1);
        add_bias<2, 1>(a1, bk, hc, l15);
        st_n<2, 1>(a1, kL + (wv * 32) * 24, 24, 0, l15, lq);
        mm_g<2, 1, 128>(xL + (wv * 32) * 136, 136, wt + OFFV(l), hc, lane, a1);
        add_bias<2, 1>(a1, bv, hc, l15);
        st_t<2, 1>(a1, vT + wv * 32, 136, 0, l15, lq);
    }
    __syncthreads();

    // attention: 4 waves x 2 i-tiles of 16 rows (P3 pattern, JT=8)
    for (int u = 0; u < 2; ++u) {
        const int iRow = wv * 32 + u * 16 + l15;
        const bool iv = vldL[iRow] != 0;
        short8 z8 = {0, 0, 0, 0, 0, 0, 0, 0};
        short8 bqf = z8;
        if (lq < 2) bqf = *(const short8*)&qL[iRow * 24 + lq * 8];
        floatx4 st[8];
#pragma unroll
        for (int jt = 0; jt < 8; ++jt) {
            short8 ak = z8;
            if (lq < 2) ak = *(const short8*)&kL[(jt * 16 + l15) * 24 + lq * 8];
            floatx4 zz = {0.f, 0.f, 0.f, 0.f};
            st[jt] = __builtin_amdgcn_mfma_f32_16x16x32_bf16(ak, bqf, zz, 0, 0, 0);
        }
        int px[8][2];
        softmax_pack<8>(st, iv, jm, px);
        floatx4 ao = {0.f, 0.f, 0.f, 0.f};
#pragma unroll
        for (int jc = 0; jc < 4; ++jc) {
            short8 av = vfrag(vT, 136, l15, jc * 32 + lq * 8);
            short8 bp = pfrag(px, jc, lq, l15);
            ao = __builtin_amdgcn_mfma_f32_16x16x32_bf16(av, bp, ao, 0, 0, 0);
        }
        short4_t w;
#pragma unroll
        for (int gg = 0; gg < 4; ++gg) w[gg] = (short)f2b(ao[gg]);
        *(short4_t*)&aob[(rowg + iRow) * 128 + hc + lq * 4] = w;
    }
}

// ---------------------------------------------------------------------------
// K2B: row-parallel O-proj + resid + LN + FFN + resid + LN. 64 rows/block.
// FINAL: writes fp32 outp (grid 16, rowbase = blk*128, rows 0..63 of group);
// else writes xg bf16 + xr fp32 (in place), grid 32, rowbase = blk*64.
// ---------------------------------------------------------------------------
template<bool FINAL>
__global__ __launch_bounds__(256, 2) void k2b(
    const ushort_t* __restrict__ ain, float* __restrict__ xr,
    const ushort_t* __restrict__ wt, int l,
    const float* __restrict__ bo_l, const float* __restrict__ l1s_l,
    const float* __restrict__ l1b_l, const float* __restrict__ b1_l,
    const float* __restrict__ b2_l, const float* __restrict__ l2s_l,
    const float* __restrict__ l2b_l,
    ushort_t* __restrict__ xg, float* __restrict__ outp)
{
    __shared__ ushort_t aL[64 * 136];
    __shared__ ushort_t hL[64 * 272];
    __shared__ float redL[512];

    const int tid = threadIdx.x, lane = tid & 63, wv = tid >> 6;
    const int l15 = lane & 15, lq = lane >> 4;
    const size_t rowbase = (size_t)blockIdx.x * (FINAL ? 128 : 64);

    // stage ain rows -> aL
#pragma unroll
    for (int it = 0; it < 4; ++it) {
        int e8 = tid + it * 256;
        int row = e8 >> 4, kg = e8 & 15;
        *(short8*)&aL[row * 136 + kg * 8] = *(const short8*)&ain[(rowbase + row) * 128 + kg * 8];
    }
    __syncthreads();

    floatx4 a2[4][2];
    float xre[4][2][4];

    // O-proj + bias + resid + LN
    mm_g<4, 2, 128>(aL, 136, wt + OFFO(l), wv * 32, lane, a2);
    add_bias<4, 2>(a2, bo_l, wv * 32, l15);
#pragma unroll
    for (int r = 0; r < 4; ++r)
#pragma unroll
        for (int c = 0; c < 2; ++c)
#pragma unroll
            for (int gg = 0; gg < 4; ++gg)
                a2[r][c][gg] += xr[(rowbase + r * 16 + lq * 4 + gg) * 128 + wv * 32 + c * 16 + l15];
    ln_norm<4, 2>(a2, redL, l1s_l, l1b_l, wv * 32, l15, lq, wv);
    save_resid<4, 2>(xre, a2);
    st_n<4, 2>(a2, aL, 136, wv * 32, l15, lq);    // aL reuse: all mm_g reads done pre-ln-sync
    __syncthreads();

    // FFN W1 + relu
    {
        floatx4 a4[4][4];
        mm_g<4, 4, 128>(aL, 136, wt + OFFW1(l), wv * 64, lane, a4);
        add_bias<4, 4>(a4, b1_l, wv * 64, l15);
#pragma unroll
        for (int r = 0; r < 4; ++r)
#pragma unroll
            for (int c = 0; c < 4; ++c)
#pragma unroll
                for (int gg = 0; gg < 4; ++gg) a4[r][c][gg] = fmaxf(a4[r][c][gg], 0.f);
        st_n<4, 4>(a4, hL, 272, wv * 64, l15, lq);
    }
    __syncthreads();

    // FFN W2 + resid + LN
    mm_g<4, 2, 256>(hL, 272, wt + OFFW2(l), wv * 32, lane, a2);
    add_bias<4, 2>(a2, b2_l, wv * 32, l15);
    add_resid_reg<4, 2>(a2, xre);
    ln_norm<4, 2>(a2, redL, l2s_l, l2b_l, wv * 32, l15, lq, wv);

    if (FINAL) {
        // rowbase = b*128; rows 0..63 are exactly output rows s<64 of batch b
#pragma unroll
        for (int r = 0; r < 4; ++r)
#pragma unroll
            for (int c = 0; c < 2; ++c)
#pragma unroll
                for (int gg = 0; gg < 4; ++gg) {
                    int row = r * 16 + lq * 4 + gg;
                    outp[((size_t)(blockIdx.x * 64 + row)) * 128 + wv * 32 + c * 16 + l15] =
                        a2[r][c][gg];
                }
    } else {
#pragma unroll
        for (int r = 0; r < 4; ++r)
#pragma unroll
            for (int c = 0; c < 2; ++c)
#pragma unroll
                for (int gg = 0; gg < 4; ++gg) {
                    size_t grow = rowbase + r * 16 + lq * 4 + gg;
                    int col = wv * 32 + c * 16 + l15;
                    float v = a2[r][c][gg];
                    xg[grow * 128 + col] = f2b(v);
                    xr[grow * 128 + col] = v;
                }
    }
}

// ---------------------------------------------------------------------------
extern "C" void kernel_launch(void* const* d_in, const int* in_sizes, int n_in,
                              void* d_out, int out_size, void* d_ws, size_t ws_size,
                              hipStream_t stream)
{
    const float* poly   = (const float*)d_in[0];
    const int*   lens   = (const int*)d_in[1];
    const float* proj_w = (const float*)d_in[2];
    const float* proj_b = (const float*)d_in[3];
    const float* pls    = (const float*)d_in[4];
    const float* plb    = (const float*)d_in[5];
    const float* pos    = (const float*)d_in[6];
    const float* Wq = (const float*)d_in[7];
    const float* bq = (const float*)d_in[8];
    const float* Wk = (const float*)d_in[9];
    const float* bk = (const float*)d_in[10];
    const float* Wv = (const float*)d_in[11];
    const float* bv = (const float*)d_in[12];
    const float* Wo = (const float*)d_in[13];
    const float* bo = (const float*)d_in[14];
    const float* l1s = (const float*)d_in[15];
    const float* l1b = (const float*)d_in[16];
    const float* W1 = (const float*)d_in[17];
    const float* b1 = (const float*)d_in[18];
    const float* W2 = (const float*)d_in[19];
    const float* b2 = (const float*)d_in[20];
    const float* l2s = (const float*)d_in[21];
    const float* l2b = (const float*)d_in[22];
    float* outp = (float*)d_out;

    char* base = (char*)d_ws;
    ushort_t* wt    = (ushort_t*)base;                 // 1,081,344 B
    ushort_t* o1buf = (ushort_t*)(base + 1081344);     // [2048][128] bf16
    float* xr0f     = (float*)(base + 1605632);        // [2048][128] fp32
    ushort_t* xgbuf = (ushort_t*)(base + 2654208);     // [2048][128] bf16
    ushort_t* aob   = (ushort_t*)(base + 3178496);     // [2048][128] bf16

    const int HH = H_ * H_, HF = H_ * FF_;
    WtArgs wa;
    wa.e[0] = {proj_w, 128, 128, 2, OFFP};
    for (int l = 0; l < 4; ++l) {
        wa.e[1 + l * 4 + 0] = {Wq + l * HH, 128, 128, 2, OFFQ(l)};
        wa.e[1 + l * 4 + 1] = {Wk + l * HH, 128, 128, 2, OFFK(l)};
        wa.e[1 + l * 4 + 2] = {Wv + l * HH, 128, 128, 2, OFFV(l)};
        wa.e[1 + l * 4 + 3] = {Wo + l * HH, 128, 128, 2, OFFO(l)};
    }
    for (int l = 0; l < 4; ++l) {
        wa.e[17 + l * 2 + 0] = {W1 + l * HF, 256, 128, 3, OFFW1(l)};
        wa.e[17 + l * 2 + 1] = {W2 + l * HF, 128, 256, 2, OFFW2(l)};
    }
    wt_kernel<<<dim3(25, 32), 256, 0, stream>>>(wa, wt);

    // ---- fused input-proj + L0 + L1(kv,q,attn) ----
    k1_mega<<<dim3(2048), 256, 0, stream>>>(
        poly, lens, wt,
        proj_b, pls, plb, pos,
        bq, bk, bv, bo, l1s, l1b, b1, b2, l2s, l2b,
        bq + H_, bk + H_, bv + H_,
        o1buf, xr0f);

    // ---- tail: 5 wide phases ----
    // B1: L1 O-proj + FFN (2048 rows)
    k2b<false><<<dim3(32), 256, 0, stream>>>(
        o1buf, xr0f, wt, 1,
        bo + H_, l1s + H_, l1b + H_, b1 + FF_, b2 + H_, l2s + H_, l2b + H_,
        xgbuf, nullptr);
    // A2: L2 QKV + attention (16 groups x 8 heads)
    k2a<<<dim3(16, 8), 256, 0, stream>>>(
        xgbuf, lens, wt, 2, bq + 2 * H_, bk + 2 * H_, bv + 2 * H_, aob);
    // B2: L2 O-proj + FFN
    k2b<false><<<dim3(32), 256, 0, stream>>>(
        aob, xr0f, wt, 2,
        bo + 2 * H_, l1s + 2 * H_, l1b + 2 * H_, b1 + 2 * FF_, b2 + 2 * H_,
        l2s + 2 * H_, l2b + 2 * H_,
        xgbuf, nullptr);
    // A3: L3 QKV + attention
    k2a<<<dim3(16, 8), 256, 0, stream>>>(
        xgbuf, lens, wt, 3, bq + 3 * H_, bk + 3 * H_, bv + 3 * H_, aob);
    // B3: L3 O-proj + FFN, final store (only rows s<64 per group)
    k2b<true><<<dim3(16), 256, 0, stream>>>(
        aob, xr0f, wt, 3,
        bo + 3 * H_, l1s + 3 * H_, l1b + 3 * H_, b1 + 3 * FF_, b2 + 3 * H_,
        l2s + 3 * H_, l2b + 3 * H_,
        nullptr, outp);
}